// Round 2
// baseline (12494.056 us; speedup 1.0000x reference)
//
#include <hip/hip_runtime.h>

// OptNet KKT layer: out = normalize(M^{-1} K^T), M = c1*Phi + c2*I (SPD, n=4096, 512 RHS).
// Blocked fp32 Cholesky + explicit per-block triangular inverses; all tile GEMMs use
// t-major LDS staging with ds_read_b128 fragments.

#define N    4096
#define NRHS 512
#define NB   128
#define LSTR 132   // padded LDS row stride (NB-wide rows), 528B = 16B-aligned, bank stride 4
#define TSTR 136   // padded LDS row stride (t-major 128-long rows), 544B aligned, bank stride 8

// ---------------- scalars: c1 = (||imp||^2+||exc||^2)/512, c2 = gamma/512 ----------------
__global__ __launch_bounds__(256) void k_scalars(const float* __restrict__ imp,
                                                 const float* __restrict__ exc,
                                                 const float* __restrict__ gamma,
                                                 float* __restrict__ c) {
  __shared__ float red[256];
  int tid = threadIdx.x;
  float s = 0.0f;
  for (int i = tid; i < 1024; i += 256) { float x = imp[i], y = exc[i]; s += x * x + y * y; }
  red[tid] = s; __syncthreads();
  for (int w = 128; w > 0; w >>= 1) { if (tid < w) red[tid] += red[tid + w]; __syncthreads(); }
  if (tid == 0) { c[0] = red[0] / 512.0f; c[1] = gamma[0] / 512.0f; }
}

// ---------------- M = c1*Phi + c2*I ----------------
__global__ __launch_bounds__(256) void k_build_M(const float* __restrict__ Phi,
                                                 const float* __restrict__ c,
                                                 float* __restrict__ M) {
  int idx = blockIdx.x * 256 + threadIdx.x;
  int base = idx * 4;
  float4 p = *(const float4*)(Phi + base);
  float c1 = c[0], c2 = c[1];
  float4 m;
  m.x = c1 * p.x; m.y = c1 * p.y; m.z = c1 * p.z; m.w = c1 * p.w;
  int r = base >> 12, c0 = base & (N - 1);
  if (r == c0)     m.x += c2;
  if (r == c0 + 1) m.y += c2;
  if (r == c0 + 2) m.z += c2;
  if (r == c0 + 3) m.w += c2;
  *(float4*)(M + base) = m;
}

// ---------------- S[i][b] = K[b][i] ----------------
__global__ __launch_bounds__(256) void k_transpose(const float* __restrict__ K,
                                                   float* __restrict__ S) {
  __shared__ float t[32][33];
  int bi = blockIdx.x, bb = blockIdx.y;
  int tx = threadIdx.x & 31, ty = threadIdx.x >> 5;
  for (int r = 0; r < 4; ++r)
    t[ty + 8 * r][tx] = K[(bb * 32 + ty + 8 * r) * N + bi * 32 + tx];
  __syncthreads();
  for (int r = 0; r < 4; ++r)
    S[(bi * 32 + ty + 8 * r) * NRHS + bb * 32 + tx] = t[tx][ty + 8 * r];
}

// ---------------- diag-block Cholesky: 16-col sub-panels ----------------
// (a) wave-sync 16x16 corner (no barriers)  (b) register TRSM of rows below
// (c) float4 rank-16 trailing update.  3 barriers per sub-panel.
__global__ __launch_bounds__(256) void k_potrf(float* __restrict__ M, int k0) {
  __shared__ float Lb[NB][LSTR];
  __shared__ float dinv_s[16];
  int tid = threadIdx.x;
  for (int idx = tid; idx < NB * 32; idx += 256) {
    int i = idx >> 5, f = idx & 31;
    *(float4*)&Lb[i][4 * f] = *(const float4*)(M + (size_t)(k0 + i) * N + k0 + 4 * f);
  }
  __syncthreads();
  volatile float* vL = (volatile float*)&Lb[0][0];
  int ty = tid >> 4, tx = tid & 15;
  for (int p = 0; p < 8; ++p) {
    int c0 = 16 * p, base = c0 + 16;
    // (a) corner Cholesky, lanes 0..15 of wave 0, wave-synchronous via volatile LDS
    if (tid < 16) {
      int l = tid;
#pragma unroll 1
      for (int j = 0; j < 16; ++j) {
        float dj = vL[(c0 + j) * LSTR + c0 + j];
        float sq = sqrtf(dj);
        float inv = 1.0f / sq;
        if (l == j) { vL[(c0 + j) * LSTR + c0 + j] = sq; dinv_s[j] = inv; }
        if (l > j) {
          float v = vL[(c0 + l) * LSTR + c0 + j] * inv;
          vL[(c0 + l) * LSTR + c0 + j] = v;
          for (int t = j + 1; t <= l; ++t)
            vL[(c0 + l) * LSTR + c0 + t] -= v * vL[(c0 + t) * LSTR + c0 + j];
        }
      }
    }
    __syncthreads();
    if (base >= NB) break;
    // (b) TRSM rows below corner: one row per thread, serial 16-step substitution in regs
    int nbl = NB - base;
    if (tid < nbl) {
      int r = base + tid;
      float xr[16];
#pragma unroll
      for (int j = 0; j < 16; ++j) {
        float v = Lb[r][c0 + j];
#pragma unroll
        for (int t = 0; t < j; ++t) v -= xr[t] * Lb[c0 + j][c0 + t];
        v *= dinv_s[j];
        xr[j] = v;
        Lb[r][c0 + j] = v;
      }
    }
    __syncthreads();
    // (c) rank-16 trailing update, lower triangle, float4 dot-16
    for (int j = base + ty; j < NB; j += 16) {
      float4 b0 = *(const float4*)&Lb[j][c0];
      float4 b1 = *(const float4*)&Lb[j][c0 + 4];
      float4 b2 = *(const float4*)&Lb[j][c0 + 8];
      float4 b3 = *(const float4*)&Lb[j][c0 + 12];
      for (int i = j + tx; i < NB; i += 16) {
        float4 a0 = *(const float4*)&Lb[i][c0];
        float4 a1 = *(const float4*)&Lb[i][c0 + 4];
        float4 a2 = *(const float4*)&Lb[i][c0 + 8];
        float4 a3 = *(const float4*)&Lb[i][c0 + 12];
        float s = a0.x * b0.x + a0.y * b0.y + a0.z * b0.z + a0.w * b0.w
                + a1.x * b1.x + a1.y * b1.y + a1.z * b1.z + a1.w * b1.w
                + a2.x * b2.x + a2.y * b2.y + a2.z * b2.z + a2.w * b2.w
                + a3.x * b3.x + a3.y * b3.y + a3.z * b3.z + a3.w * b3.w;
        Lb[i][j] -= s;
      }
    }
    __syncthreads();
  }
  for (int idx = tid; idx < NB * 32; idx += 256) {
    int i = idx >> 5, f = idx & 31;
    *(float4*)(M + (size_t)(k0 + i) * N + k0 + 4 * f) = *(const float4*)&Lb[i][4 * f];
  }
}

// ---------------- U = L^{-1} for diag block; writes row-major U and transposed UT ----------------
__global__ __launch_bounds__(256) void k_triinv(const float* __restrict__ M,
                                                float* __restrict__ U,
                                                float* __restrict__ UT, int k0) {
  __shared__ float Lb[NB][NB + 1];
  volatile __shared__ float X[16][NB];
  int tid = threadIdx.x;
  for (int idx = tid; idx < NB * NB; idx += 256) {
    int i = idx >> 7, j = idx & 127;
    Lb[i][j] = M[(size_t)(k0 + i) * N + (k0 + j)];
  }
  __syncthreads();
  int g = tid >> 4, l = tid & 15;
  int c = blockIdx.x * 16 + g;
  for (int i = l; i < NB; i += 16) X[g][i] = 0.0f;
  float inv_cc = 1.0f / Lb[c][c];
  if (l == 0) X[g][c] = inv_cc;
  for (int i = c + 1; i < NB; ++i) {
    float s = 0.0f;
    for (int t = c + l; t < i; t += 16) s += Lb[i][t] * X[g][t];
    for (int m = 8; m; m >>= 1) s += __shfl_xor(s, m, 16);
    if (l == 0) X[g][i] = -s / Lb[i][i];
  }
  __syncthreads();
  for (int idx = tid; idx < NB * 16; idx += 256) {
    int i = idx >> 4, cl = idx & 15;
    float v = X[cl][i];
    U[(size_t)i * NB + blockIdx.x * 16 + cl] = v;
    UT[(size_t)(blockIdx.x * 16 + cl) * NB + i] = v;
  }
}

// ---------------- panel TRSM as GEMM: P := P_old * U^T ----------------
__global__ __launch_bounds__(256) void k_trsm(float* __restrict__ M,
                                              const float* __restrict__ UT, int k0) {
  __shared__ float Ut[NB][LSTR];   // Ut[t][j] = U[j][t]
  __shared__ float At[16][TSTR];   // At[t][r] = A[r][tch+t]
  int tid = threadIdx.x;
  int r0 = k0 + NB + blockIdx.x * NB;
  for (int idx = tid; idx < NB * 32; idx += 256) {
    int t = idx >> 5, f = idx & 31;
    *(float4*)&Ut[t][4 * f] = *(const float4*)(UT + (size_t)t * NB + 4 * f);
  }
  int i0 = (tid >> 4) * 8, j0 = (tid & 15) * 8;
  float acc[8][8] = {};
  for (int tch = 0; tch < NB; tch += 16) {
    for (int idx = tid; idx < 512; idx += 256) {
      int r = idx >> 2, q = idx & 3;
      const float4 v = *(const float4*)(M + (size_t)(r0 + r) * N + k0 + tch + 4 * q);
      At[4 * q + 0][r] = v.x; At[4 * q + 1][r] = v.y;
      At[4 * q + 2][r] = v.z; At[4 * q + 3][r] = v.w;
    }
    __syncthreads();
#pragma unroll 4
    for (int t = 0; t < 16; ++t) {
      float4 a0 = *(const float4*)&At[t][i0];
      float4 a1 = *(const float4*)&At[t][i0 + 4];
      float4 u0 = *(const float4*)&Ut[tch + t][j0];
      float4 u1 = *(const float4*)&Ut[tch + t][j0 + 4];
      float av[8] = {a0.x, a0.y, a0.z, a0.w, a1.x, a1.y, a1.z, a1.w};
      float uv[8] = {u0.x, u0.y, u0.z, u0.w, u1.x, u1.y, u1.z, u1.w};
#pragma unroll
      for (int q = 0; q < 8; ++q)
#pragma unroll
        for (int w = 0; w < 8; ++w) acc[q][w] += av[q] * uv[w];
    }
    __syncthreads();
  }
  for (int q = 0; q < 8; ++q) {
    float* mp = M + (size_t)(r0 + i0 + q) * N + k0 + j0;
    float4 x0, x1;
    x0.x = acc[q][0]; x0.y = acc[q][1]; x0.z = acc[q][2]; x0.w = acc[q][3];
    x1.x = acc[q][4]; x1.y = acc[q][5]; x1.z = acc[q][6]; x1.w = acc[q][7];
    *(float4*)mp = x0; *((float4*)mp + 1) = x1;
  }
}

// ---------------- SYRK trailing update: C -= P P^T (lower tiles) ----------------
__global__ __launch_bounds__(256) void k_syrk(float* __restrict__ M, int k0) {
  int br = blockIdx.y, bc = blockIdx.x;
  if (bc > br) return;
  int t0 = k0 + NB;
  int r0 = t0 + br * NB, c0 = t0 + bc * NB;
  __shared__ float Pa[16][TSTR], Pb[16][TSTR];
  int tid = threadIdx.x;
  int rr = (tid >> 4) * 8, cc = (tid & 15) * 8;
  float acc[8][8] = {};
  for (int tch = 0; tch < NB; tch += 16) {
    for (int idx = tid; idx < 1024; idx += 256) {
      int sel = idx >> 9, id2 = idx & 511;
      int r = id2 >> 2, q = id2 & 3;
      const float4 v = *(const float4*)(M + (size_t)((sel ? c0 : r0) + r) * N + k0 + tch + 4 * q);
      float* dst = sel ? &Pb[0][0] : &Pa[0][0];
      dst[(4 * q + 0) * TSTR + r] = v.x;
      dst[(4 * q + 1) * TSTR + r] = v.y;
      dst[(4 * q + 2) * TSTR + r] = v.z;
      dst[(4 * q + 3) * TSTR + r] = v.w;
    }
    __syncthreads();
#pragma unroll 4
    for (int t = 0; t < 16; ++t) {
      float4 a0 = *(const float4*)&Pa[t][rr];
      float4 a1 = *(const float4*)&Pa[t][rr + 4];
      float4 b0 = *(const float4*)&Pb[t][cc];
      float4 b1 = *(const float4*)&Pb[t][cc + 4];
      float av[8] = {a0.x, a0.y, a0.z, a0.w, a1.x, a1.y, a1.z, a1.w};
      float bv[8] = {b0.x, b0.y, b0.z, b0.w, b1.x, b1.y, b1.z, b1.w};
#pragma unroll
      for (int q = 0; q < 8; ++q)
#pragma unroll
        for (int w = 0; w < 8; ++w) acc[q][w] += av[q] * bv[w];
    }
    __syncthreads();
  }
  for (int q = 0; q < 8; ++q) {
    float* mp = M + (size_t)(r0 + rr + q) * N + c0 + cc;
    float4 x0 = *(float4*)mp, x1 = *((float4*)mp + 1);
    x0.x -= acc[q][0]; x0.y -= acc[q][1]; x0.z -= acc[q][2]; x0.w -= acc[q][3];
    x1.x -= acc[q][4]; x1.y -= acc[q][5]; x1.z -= acc[q][6]; x1.w -= acc[q][7];
    *(float4*)mp = x0; *((float4*)mp + 1) = x1;
  }
}

// ---------------- forward solve diag step: X = U * R (in place on S) ----------------
__global__ __launch_bounds__(256) void k_solve_fwd(float* __restrict__ S,
                                                   const float* __restrict__ UT, int k0) {
  __shared__ float Ult[NB][LSTR];  // Ult[t][i] = U[i][t]
  __shared__ float Rl[16][LSTR];
  int tid = threadIdx.x;
  int b0 = blockIdx.x * NB;
  for (int idx = tid; idx < NB * 32; idx += 256) {
    int t = idx >> 5, f = idx & 31;
    *(float4*)&Ult[t][4 * f] = *(const float4*)(UT + (size_t)t * NB + 4 * f);
  }
  int i0 = (tid >> 4) * 8, bl = (tid & 15) * 8;
  float acc[8][8] = {};
  for (int tch = 0; tch < NB; tch += 16) {
    for (int idx = tid; idx < 512; idx += 256) {
      int t = idx >> 5, f = idx & 31;
      *(float4*)&Rl[t][4 * f] = *(const float4*)(S + (size_t)(k0 + tch + t) * NRHS + b0 + 4 * f);
    }
    __syncthreads();
#pragma unroll 4
    for (int t = 0; t < 16; ++t) {
      float4 u0 = *(const float4*)&Ult[tch + t][i0];
      float4 u1 = *(const float4*)&Ult[tch + t][i0 + 4];
      float4 r0v = *(const float4*)&Rl[t][bl];
      float4 r1v = *(const float4*)&Rl[t][bl + 4];
      float uv[8] = {u0.x, u0.y, u0.z, u0.w, u1.x, u1.y, u1.z, u1.w};
      float rv[8] = {r0v.x, r0v.y, r0v.z, r0v.w, r1v.x, r1v.y, r1v.z, r1v.w};
#pragma unroll
      for (int q = 0; q < 8; ++q)
#pragma unroll
        for (int w = 0; w < 8; ++w) acc[q][w] += uv[q] * rv[w];
    }
    __syncthreads();
  }
  for (int q = 0; q < 8; ++q) {
    float* sp = S + (size_t)(k0 + i0 + q) * NRHS + b0 + bl;
    float4 x0, x1;
    x0.x = acc[q][0]; x0.y = acc[q][1]; x0.z = acc[q][2]; x0.w = acc[q][3];
    x1.x = acc[q][4]; x1.y = acc[q][5]; x1.z = acc[q][6]; x1.w = acc[q][7];
    *(float4*)sp = x0; *((float4*)sp + 1) = x1;
  }
}

// ---------------- backward solve diag step: X = U^T * R ----------------
__global__ __launch_bounds__(256) void k_solve_bwd(float* __restrict__ S,
                                                   const float* __restrict__ U, int k0) {
  __shared__ float Ul[NB][LSTR];   // row-major U
  __shared__ float Rl[16][LSTR];
  int tid = threadIdx.x;
  int b0 = blockIdx.x * NB;
  for (int idx = tid; idx < NB * 32; idx += 256) {
    int i = idx >> 5, f = idx & 31;
    *(float4*)&Ul[i][4 * f] = *(const float4*)(U + (size_t)i * NB + 4 * f);
  }
  int i0 = (tid >> 4) * 8, bl = (tid & 15) * 8;
  float acc[8][8] = {};
  for (int tch = 0; tch < NB; tch += 16) {
    for (int idx = tid; idx < 512; idx += 256) {
      int t = idx >> 5, f = idx & 31;
      *(float4*)&Rl[t][4 * f] = *(const float4*)(S + (size_t)(k0 + tch + t) * NRHS + b0 + 4 * f);
    }
    __syncthreads();
#pragma unroll 4
    for (int t = 0; t < 16; ++t) {
      float4 u0 = *(const float4*)&Ul[tch + t][i0];   // U[tch+t][i0..] = U^T fragment
      float4 u1 = *(const float4*)&Ul[tch + t][i0 + 4];
      float4 r0v = *(const float4*)&Rl[t][bl];
      float4 r1v = *(const float4*)&Rl[t][bl + 4];
      float uv[8] = {u0.x, u0.y, u0.z, u0.w, u1.x, u1.y, u1.z, u1.w};
      float rv[8] = {r0v.x, r0v.y, r0v.z, r0v.w, r1v.x, r1v.y, r1v.z, r1v.w};
#pragma unroll
      for (int q = 0; q < 8; ++q)
#pragma unroll
        for (int w = 0; w < 8; ++w) acc[q][w] += uv[q] * rv[w];
    }
    __syncthreads();
  }
  for (int q = 0; q < 8; ++q) {
    float* sp = S + (size_t)(k0 + i0 + q) * NRHS + b0 + bl;
    float4 x0, x1;
    x0.x = acc[q][0]; x0.y = acc[q][1]; x0.z = acc[q][2]; x0.w = acc[q][3];
    x1.x = acc[q][4]; x1.y = acc[q][5]; x1.z = acc[q][6]; x1.w = acc[q][7];
    *(float4*)sp = x0; *((float4*)sp + 1) = x1;
  }
}

// ---------------- forward update: S[below] -= L[below,k] * X_k ----------------
__global__ __launch_bounds__(256) void k_fwd_update(float* __restrict__ S,
                                                    const float* __restrict__ M, int k0) {
  __shared__ float At[16][TSTR];   // At[t][r] = L[r0+r][k0+tch+t]
  __shared__ float Bl[16][LSTR];   // Bl[t][b] = X[k0+tch+t][b0+b]
  int tid = threadIdx.x;
  int r0 = k0 + NB + blockIdx.y * NB;
  int b0 = blockIdx.x * NB;
  int i0 = (tid >> 4) * 8, bl = (tid & 15) * 8;
  float acc[8][8] = {};
  for (int tch = 0; tch < NB; tch += 16) {
    for (int idx = tid; idx < 512; idx += 256) {
      int r = idx >> 2, q = idx & 3;
      const float4 v = *(const float4*)(M + (size_t)(r0 + r) * N + k0 + tch + 4 * q);
      At[4 * q + 0][r] = v.x; At[4 * q + 1][r] = v.y;
      At[4 * q + 2][r] = v.z; At[4 * q + 3][r] = v.w;
    }
    for (int idx = tid; idx < 512; idx += 256) {
      int t = idx >> 5, f = idx & 31;
      *(float4*)&Bl[t][4 * f] = *(const float4*)(S + (size_t)(k0 + tch + t) * NRHS + b0 + 4 * f);
    }
    __syncthreads();
#pragma unroll 4
    for (int t = 0; t < 16; ++t) {
      float4 a0 = *(const float4*)&At[t][i0];
      float4 a1 = *(const float4*)&At[t][i0 + 4];
      float4 b0v = *(const float4*)&Bl[t][bl];
      float4 b1v = *(const float4*)&Bl[t][bl + 4];
      float av[8] = {a0.x, a0.y, a0.z, a0.w, a1.x, a1.y, a1.z, a1.w};
      float bv[8] = {b0v.x, b0v.y, b0v.z, b0v.w, b1v.x, b1v.y, b1v.z, b1v.w};
#pragma unroll
      for (int q = 0; q < 8; ++q)
#pragma unroll
        for (int w = 0; w < 8; ++w) acc[q][w] += av[q] * bv[w];
    }
    __syncthreads();
  }
  for (int q = 0; q < 8; ++q) {
    float* sp = S + (size_t)(r0 + i0 + q) * NRHS + b0 + bl;
    float4 x0 = *(float4*)sp, x1 = *((float4*)sp + 1);
    x0.x -= acc[q][0]; x0.y -= acc[q][1]; x0.z -= acc[q][2]; x0.w -= acc[q][3];
    x1.x -= acc[q][4]; x1.y -= acc[q][5]; x1.z -= acc[q][6]; x1.w -= acc[q][7];
    *(float4*)sp = x0; *((float4*)sp + 1) = x1;
  }
}

// ---------------- backward update: S[above] -= L^T[above,k] * X_k ----------------
__global__ __launch_bounds__(256) void k_bwd_update(float* __restrict__ S,
                                                    const float* __restrict__ M, int k0) {
  __shared__ float Al[16][LSTR];   // Al[t][r] = L[k0+tch+t][r0+r]
  __shared__ float Bl[16][LSTR];
  int tid = threadIdx.x;
  int r0 = blockIdx.y * NB;
  int b0 = blockIdx.x * NB;
  int i0 = (tid >> 4) * 8, bl = (tid & 15) * 8;
  float acc[8][8] = {};
  for (int tch = 0; tch < NB; tch += 16) {
    for (int idx = tid; idx < 512; idx += 256) {
      int t = idx >> 5, f = idx & 31;
      *(float4*)&Al[t][4 * f] = *(const float4*)(M + (size_t)(k0 + tch + t) * N + r0 + 4 * f);
      *(float4*)&Bl[t][4 * f] = *(const float4*)(S + (size_t)(k0 + tch + t) * NRHS + b0 + 4 * f);
    }
    __syncthreads();
#pragma unroll 4
    for (int t = 0; t < 16; ++t) {
      float4 a0 = *(const float4*)&Al[t][i0];
      float4 a1 = *(const float4*)&Al[t][i0 + 4];
      float4 b0v = *(const float4*)&Bl[t][bl];
      float4 b1v = *(const float4*)&Bl[t][bl + 4];
      float av[8] = {a0.x, a0.y, a0.z, a0.w, a1.x, a1.y, a1.z, a1.w};
      float bv[8] = {b0v.x, b0v.y, b0v.z, b0v.w, b1v.x, b1v.y, b1v.z, b1v.w};
#pragma unroll
      for (int q = 0; q < 8; ++q)
#pragma unroll
        for (int w = 0; w < 8; ++w) acc[q][w] += av[q] * bv[w];
    }
    __syncthreads();
  }
  for (int q = 0; q < 8; ++q) {
    float* sp = S + (size_t)(r0 + i0 + q) * NRHS + b0 + bl;
    float4 x0 = *(float4*)sp, x1 = *((float4*)sp + 1);
    x0.x -= acc[q][0]; x0.y -= acc[q][1]; x0.z -= acc[q][2]; x0.w -= acc[q][3];
    x1.x -= acc[q][4]; x1.y -= acc[q][5]; x1.z -= acc[q][6]; x1.w -= acc[q][7];
    *(float4*)sp = x0; *((float4*)sp + 1) = x1;
  }
}

// ---------------- denom + normalize + transpose to output ----------------
__global__ __launch_bounds__(256) void k_final(const float* __restrict__ S,
                                               const float* __restrict__ K,
                                               const float* __restrict__ a_ptr,
                                               float* __restrict__ out) {
  __shared__ float red[256];
  int b = blockIdx.x, tid = threadIdx.x;
  float s = 0.0f;
  for (int i = tid; i < N; i += 256) s += S[(size_t)i * NRHS + b] * K[(size_t)b * N + i];
  red[tid] = s; __syncthreads();
  for (int w = 128; w > 0; w >>= 1) { if (tid < w) red[tid] += red[tid + w]; __syncthreads(); }
  float inv = 1.0f / (a_ptr[0] * red[0]);
  for (int i = tid; i < N; i += 256) out[(size_t)b * N + i] = S[(size_t)i * NRHS + b] * inv;
}

extern "C" void kernel_launch(void* const* d_in, const int* in_sizes, int n_in,
                              void* d_out, int out_size, void* d_ws, size_t ws_size,
                              hipStream_t stream) {
  const float* Kb    = (const float*)d_in[0];
  const float* a     = (const float*)d_in[1];
  const float* exc   = (const float*)d_in[2];
  const float* imp   = (const float*)d_in[3];
  const float* Phi   = (const float*)d_in[4];
  const float* gamma = (const float*)d_in[5];
  float* out = (float*)d_out;

  float* M  = (float*)d_ws;                        // n*n            (64 MiB)
  float* S  = M + (size_t)N * N;                   // n*NRHS         (8 MiB)
  float* U  = S + (size_t)N * NRHS;                // 32 * 128*128   (2 MiB)
  float* UT = U + (size_t)32 * NB * NB;            // 32 * 128*128   (2 MiB)
  float* c  = UT + (size_t)32 * NB * NB;           // scalars

  k_scalars<<<1, 256, 0, stream>>>(imp, exc, gamma, c);
  k_build_M<<<(N / 16) * (N / 64), 256, 0, stream>>>(Phi, c, M);
  k_transpose<<<dim3(N / 32, NRHS / 32), 256, 0, stream>>>(Kb, S);

  for (int k = 0; k < 32; ++k) {
    int k0 = k * NB;
    float* Uk  = U  + (size_t)k * NB * NB;
    float* UTk = UT + (size_t)k * NB * NB;
    k_potrf<<<1, 256, 0, stream>>>(M, k0);
    k_triinv<<<8, 256, 0, stream>>>(M, Uk, UTk, k0);
    int Tk = 31 - k;
    if (Tk > 0) {
      k_trsm<<<Tk, 256, 0, stream>>>(M, UTk, k0);
      k_syrk<<<dim3(Tk, Tk), 256, 0, stream>>>(M, k0);
    }
  }
  for (int k = 0; k < 32; ++k) {
    int k0 = k * NB;
    k_solve_fwd<<<NRHS / NB, 256, 0, stream>>>(S, UT + (size_t)k * NB * NB, k0);
    if (k < 31) k_fwd_update<<<dim3(NRHS / NB, 31 - k), 256, 0, stream>>>(S, M, k0);
  }
  for (int k = 31; k >= 0; --k) {
    int k0 = k * NB;
    k_solve_bwd<<<NRHS / NB, 256, 0, stream>>>(S, U + (size_t)k * NB * NB, k0);
    if (k > 0) k_bwd_update<<<dim3(NRHS / NB, k), 256, 0, stream>>>(S, M, k0);
  }
  k_final<<<NRHS, 256, 0, stream>>>(S, Kb, a, out);
}

// Round 3
// 8988.935 us; speedup vs baseline: 1.3899x; 1.3899x over previous
//
#include <hip/hip_runtime.h>

// OptNet KKT layer: out = normalize(M^{-1} K^T), M = c1*Phi + c2*I (SPD, n=4096, 512 RHS).
// Blocked fp32 Cholesky. Per 128-block: fused potrf + L^{-1} in ONE grid-1 kernel
// (register-resident 32x32 corners via shfl). Solve phases fused to one dispatch per
// block-step with redundant diag-solve per block.

#define N    4096
#define NRHS 512
#define NB   128
#define LSTR 132   // padded LDS row stride for 128-wide rows
#define TSTR 136   // padded LDS row stride for t-major staging

// ---------------- scalars: c1 = (||imp||^2+||exc||^2)/512, c2 = gamma/512 ----------------
__global__ __launch_bounds__(256) void k_scalars(const float* __restrict__ imp,
                                                 const float* __restrict__ exc,
                                                 const float* __restrict__ gamma,
                                                 float* __restrict__ c) {
  __shared__ float red[256];
  int tid = threadIdx.x;
  float s = 0.0f;
  for (int i = tid; i < 1024; i += 256) { float x = imp[i], y = exc[i]; s += x * x + y * y; }
  red[tid] = s; __syncthreads();
  for (int w = 128; w > 0; w >>= 1) { if (tid < w) red[tid] += red[tid + w]; __syncthreads(); }
  if (tid == 0) { c[0] = red[0] / 512.0f; c[1] = gamma[0] / 512.0f; }
}

// ---------------- M = c1*Phi + c2*I ----------------
__global__ __launch_bounds__(256) void k_build_M(const float* __restrict__ Phi,
                                                 const float* __restrict__ c,
                                                 float* __restrict__ M) {
  int idx = blockIdx.x * 256 + threadIdx.x;
  int base = idx * 4;
  float4 p = *(const float4*)(Phi + base);
  float c1 = c[0], c2 = c[1];
  float4 m;
  m.x = c1 * p.x; m.y = c1 * p.y; m.z = c1 * p.z; m.w = c1 * p.w;
  int r = base >> 12, c0 = base & (N - 1);
  if (r == c0)     m.x += c2;
  if (r == c0 + 1) m.y += c2;
  if (r == c0 + 2) m.z += c2;
  if (r == c0 + 3) m.w += c2;
  *(float4*)(M + base) = m;
}

// ---------------- S[i][b] = K[b][i] ----------------
__global__ __launch_bounds__(256) void k_transpose(const float* __restrict__ K,
                                                   float* __restrict__ S) {
  __shared__ float t[32][33];
  int bi = blockIdx.x, bb = blockIdx.y;
  int tx = threadIdx.x & 31, ty = threadIdx.x >> 5;
  for (int r = 0; r < 4; ++r)
    t[ty + 8 * r][tx] = K[(size_t)(bb * 32 + ty + 8 * r) * N + bi * 32 + tx];
  __syncthreads();
  for (int r = 0; r < 4; ++r)
    S[(size_t)(bi * 32 + ty + 8 * r) * NRHS + bb * 32 + tx] = t[tx][ty + 8 * r];
}

// ---------------- fused: Cholesky of 128x128 diag block + U = L^{-1} (and UT) ----------------
// One block, 1024 threads. 32x32 corners factored in registers by lanes 0..31 of wave 0
// (static-unrolled shfl, no LDS latency chain); strip TRSM + rank-32 trailing by all threads;
// U assembled from corner inverses by block wavefronts.
__global__ __launch_bounds__(1024) void k_potrf_inv(float* __restrict__ M,
                                                    float* __restrict__ U,
                                                    float* __restrict__ UT,
                                                    int k0) {
  __shared__ float Lb[NB][LSTR];
  __shared__ float Us[NB][LSTR];
  __shared__ float Tl[3][32][33];
  int tid = threadIdx.x;
  // stage in diag block
  for (int idx = tid; idx < NB * 32; idx += 1024) {
    int i = idx >> 5, f = idx & 31;
    *(float4*)&Lb[i][4 * f] = *(const float4*)(M + (size_t)(k0 + i) * N + k0 + 4 * f);
  }
  // zero U
  for (int idx = tid; idx < NB * 32; idx += 1024) {
    int i = idx >> 5, f = idx & 31;
    *(float4*)&Us[i][4 * f] = make_float4(0.f, 0.f, 0.f, 0.f);
  }
  __syncthreads();
  int l = tid;
  for (int p = 0; p < 4; ++p) {
    int b0 = 32 * p;
    if (tid < 32) {
      // load corner rows into registers
      float r[32];
#pragma unroll
      for (int t = 0; t < 32; ++t) r[t] = Lb[b0 + l][b0 + t];
      // in-register Cholesky (right-looking, rank-1 per column)
#pragma unroll
      for (int j = 0; j < 32; ++j) {
        float ajj = __shfl(r[j], j);
        float sq = sqrtf(ajj);
        float inv = 1.0f / sq;
        if (l == j) r[j] = sq;
        else if (l > j) r[j] *= inv;
#pragma unroll
        for (int t = j + 1; t < 32; ++t) {
          float Ltj = __shfl(r[j], t);
          if (l >= t) r[t] -= r[j] * Ltj;
        }
      }
      // write corner L back (lower incl diag)
#pragma unroll
      for (int t = 0; t < 32; ++t) if (t <= l) Lb[b0 + l][b0 + t] = r[t];
      // corner inverse V = L_corner^{-1}: lane l computes column l
      float x[32];
#pragma unroll
      for (int i = 0; i < 32; ++i) {
        float s = 0.0f;
#pragma unroll
        for (int t = 0; t < i; ++t) {
          float Lit = __shfl(r[t], i);
          s += Lit * x[t];
        }
        float di = __shfl(r[i], i);
        float dl = (l == i) ? 1.0f : 0.0f;
        x[i] = (dl - s) / di;
      }
      // V into the diag block of Us (column l; zeros above diag come naturally)
#pragma unroll
      for (int i = 0; i < 32; ++i) Us[b0 + i][b0 + l] = x[i];
    }
    __syncthreads();
    int base = b0 + 32;
    int nbl = NB - base;
    if (nbl > 0) {
      // strip TRSM: Lb[base+r][b0+c] = sum_t A[base+r][b0+t] * V[c][t]
      float pv[3];
      int cnt = nbl * 32;
#pragma unroll
      for (int e = 0; e < 3; ++e) {
        int idx = tid + e * 1024;
        if (idx < cnt) {
          int r = idx >> 5, cc = idx & 31;
          float s = 0.0f;
#pragma unroll
          for (int t = 0; t < 32; ++t)
            s += Lb[base + r][b0 + t] * Us[b0 + cc][b0 + t];
          pv[e] = s;
        }
      }
      __syncthreads();
#pragma unroll
      for (int e = 0; e < 3; ++e) {
        int idx = tid + e * 1024;
        if (idx < cnt) {
          int r = idx >> 5, cc = idx & 31;
          Lb[base + r][b0 + cc] = pv[e];
        }
      }
      __syncthreads();
      // rank-32 trailing update (lower incl diag)
      int tot = nbl * nbl;
      for (int idx = tid; idx < tot; idx += 1024) {
        int i = idx / nbl, j = idx - i * nbl;
        if (j <= i) {
          float4 a0 = *(const float4*)&Lb[base + i][b0];
          float4 a1 = *(const float4*)&Lb[base + i][b0 + 4];
          float4 a2 = *(const float4*)&Lb[base + i][b0 + 8];
          float4 a3 = *(const float4*)&Lb[base + i][b0 + 12];
          float4 a4 = *(const float4*)&Lb[base + i][b0 + 16];
          float4 a5 = *(const float4*)&Lb[base + i][b0 + 20];
          float4 a6 = *(const float4*)&Lb[base + i][b0 + 24];
          float4 a7 = *(const float4*)&Lb[base + i][b0 + 28];
          float4 b0v = *(const float4*)&Lb[base + j][b0];
          float4 b1v = *(const float4*)&Lb[base + j][b0 + 4];
          float4 b2v = *(const float4*)&Lb[base + j][b0 + 8];
          float4 b3v = *(const float4*)&Lb[base + j][b0 + 12];
          float4 b4v = *(const float4*)&Lb[base + j][b0 + 16];
          float4 b5v = *(const float4*)&Lb[base + j][b0 + 20];
          float4 b6v = *(const float4*)&Lb[base + j][b0 + 24];
          float4 b7v = *(const float4*)&Lb[base + j][b0 + 28];
          float s = a0.x*b0v.x + a0.y*b0v.y + a0.z*b0v.z + a0.w*b0v.w
                  + a1.x*b1v.x + a1.y*b1v.y + a1.z*b1v.z + a1.w*b1v.w
                  + a2.x*b2v.x + a2.y*b2v.y + a2.z*b2v.z + a2.w*b2v.w
                  + a3.x*b3v.x + a3.y*b3v.y + a3.z*b3v.z + a3.w*b3v.w
                  + a4.x*b4v.x + a4.y*b4v.y + a4.z*b4v.z + a4.w*b4v.w
                  + a5.x*b5v.x + a5.y*b5v.y + a5.z*b5v.z + a5.w*b5v.w
                  + a6.x*b6v.x + a6.y*b6v.y + a6.z*b6v.z + a6.w*b6v.w
                  + a7.x*b7v.x + a7.y*b7v.y + a7.z*b7v.z + a7.w*b7v.w;
          Lb[base + i][base + j] -= s;
        }
      }
      __syncthreads();
    }
  }
  // assemble off-diagonal blocks of U = L^{-1}: U_ij = -V_i * (sum_{t=j..i-1} L_it U_tj)
  for (int d = 1; d <= 3; ++d) {
    int nb = 4 - d;
    int blk = tid >> 8;
    int id2 = tid & 255;
    if (blk < nb) {
      int bi = blk + d, bj = blk;
#pragma unroll
      for (int e = 0; e < 4; ++e) {
        int el = id2 + 256 * e;
        int rr = el >> 5, cc = el & 31;
        float s = 0.0f;
        for (int t = 32 * bj; t < 32 * bi; ++t)
          s += Lb[32 * bi + rr][t] * Us[t][32 * bj + cc];
        Tl[blk][rr][cc] = s;
      }
    }
    __syncthreads();
    if (blk < nb) {
      int bi = blk + d, bj = blk;
#pragma unroll
      for (int e = 0; e < 4; ++e) {
        int el = id2 + 256 * e;
        int rr = el >> 5, cc = el & 31;
        float s = 0.0f;
#pragma unroll
        for (int t = 0; t < 32; ++t)
          s += Us[32 * bi + rr][32 * bi + t] * Tl[blk][t][cc];
        Us[32 * bi + rr][32 * bj + cc] = -s;
      }
    }
    __syncthreads();
  }
  // write L to M, U row-major, UT transposed (coalesced global writes)
  for (int idx = tid; idx < NB * 32; idx += 1024) {
    int i = idx >> 5, f = idx & 31;
    *(float4*)(M + (size_t)(k0 + i) * N + k0 + 4 * f) = *(const float4*)&Lb[i][4 * f];
    *(float4*)(U + (size_t)i * NB + 4 * f) = *(const float4*)&Us[i][4 * f];
    float4 v;
    v.x = Us[4 * f + 0][i]; v.y = Us[4 * f + 1][i];
    v.z = Us[4 * f + 2][i]; v.w = Us[4 * f + 3][i];
    *(float4*)(UT + (size_t)i * NB + 4 * f) = v;   // UT[i][f..] = U[f..][i]
  }
}

// ---------------- panel TRSM as GEMM: P := P_old * U^T ----------------
__global__ __launch_bounds__(256) void k_trsm(float* __restrict__ M,
                                              const float* __restrict__ UT, int k0) {
  __shared__ float Ut[NB][LSTR];   // Ut[t][j] = U[j][t]
  __shared__ float At[16][TSTR];   // At[t][r] = A[r][tch+t]
  int tid = threadIdx.x;
  int r0 = k0 + NB + blockIdx.x * NB;
  for (int idx = tid; idx < NB * 32; idx += 256) {
    int t = idx >> 5, f = idx & 31;
    *(float4*)&Ut[t][4 * f] = *(const float4*)(UT + (size_t)t * NB + 4 * f);
  }
  int i0 = (tid >> 4) * 8, j0 = (tid & 15) * 8;
  float acc[8][8] = {};
  for (int tch = 0; tch < NB; tch += 16) {
    for (int idx = tid; idx < 512; idx += 256) {
      int r = idx >> 2, q = idx & 3;
      const float4 v = *(const float4*)(M + (size_t)(r0 + r) * N + k0 + tch + 4 * q);
      At[4 * q + 0][r] = v.x; At[4 * q + 1][r] = v.y;
      At[4 * q + 2][r] = v.z; At[4 * q + 3][r] = v.w;
    }
    __syncthreads();
#pragma unroll 4
    for (int t = 0; t < 16; ++t) {
      float4 a0 = *(const float4*)&At[t][i0];
      float4 a1 = *(const float4*)&At[t][i0 + 4];
      float4 u0 = *(const float4*)&Ut[tch + t][j0];
      float4 u1 = *(const float4*)&Ut[tch + t][j0 + 4];
      float av[8] = {a0.x, a0.y, a0.z, a0.w, a1.x, a1.y, a1.z, a1.w};
      float uv[8] = {u0.x, u0.y, u0.z, u0.w, u1.x, u1.y, u1.z, u1.w};
#pragma unroll
      for (int q = 0; q < 8; ++q)
#pragma unroll
        for (int w = 0; w < 8; ++w) acc[q][w] += av[q] * uv[w];
    }
    __syncthreads();
  }
  for (int q = 0; q < 8; ++q) {
    float* mp = M + (size_t)(r0 + i0 + q) * N + k0 + j0;
    float4 x0 = {acc[q][0], acc[q][1], acc[q][2], acc[q][3]};
    float4 x1 = {acc[q][4], acc[q][5], acc[q][6], acc[q][7]};
    *(float4*)mp = x0; *((float4*)mp + 1) = x1;
  }
}

// ---------------- SYRK trailing update: C -= P P^T (lower tiles) ----------------
__global__ __launch_bounds__(256) void k_syrk(float* __restrict__ M, int k0) {
  int br = blockIdx.y, bc = blockIdx.x;
  if (bc > br) return;
  int t0 = k0 + NB;
  int r0 = t0 + br * NB, c0 = t0 + bc * NB;
  __shared__ float Pa[16][TSTR], Pb[16][TSTR];
  int tid = threadIdx.x;
  int rr = (tid >> 4) * 8, cc = (tid & 15) * 8;
  float acc[8][8] = {};
  for (int tch = 0; tch < NB; tch += 16) {
    for (int idx = tid; idx < 1024; idx += 256) {
      int sel = idx >> 9, id2 = idx & 511;
      int r = id2 >> 2, q = id2 & 3;
      const float4 v = *(const float4*)(M + (size_t)((sel ? c0 : r0) + r) * N + k0 + tch + 4 * q);
      float* dst = sel ? &Pb[0][0] : &Pa[0][0];
      dst[(4 * q + 0) * TSTR + r] = v.x;
      dst[(4 * q + 1) * TSTR + r] = v.y;
      dst[(4 * q + 2) * TSTR + r] = v.z;
      dst[(4 * q + 3) * TSTR + r] = v.w;
    }
    __syncthreads();
#pragma unroll 4
    for (int t = 0; t < 16; ++t) {
      float4 a0 = *(const float4*)&Pa[t][rr];
      float4 a1 = *(const float4*)&Pa[t][rr + 4];
      float4 b0 = *(const float4*)&Pb[t][cc];
      float4 b1 = *(const float4*)&Pb[t][cc + 4];
      float av[8] = {a0.x, a0.y, a0.z, a0.w, a1.x, a1.y, a1.z, a1.w};
      float bv[8] = {b0.x, b0.y, b0.z, b0.w, b1.x, b1.y, b1.z, b1.w};
#pragma unroll
      for (int q = 0; q < 8; ++q)
#pragma unroll
        for (int w = 0; w < 8; ++w) acc[q][w] += av[q] * bv[w];
    }
    __syncthreads();
  }
  for (int q = 0; q < 8; ++q) {
    float* mp = M + (size_t)(r0 + rr + q) * N + c0 + cc;
    float4 x0 = *(float4*)mp, x1 = *((float4*)mp + 1);
    x0.x -= acc[q][0]; x0.y -= acc[q][1]; x0.z -= acc[q][2]; x0.w -= acc[q][3];
    x1.x -= acc[q][4]; x1.y -= acc[q][5]; x1.z -= acc[q][6]; x1.w -= acc[q][7];
    *(float4*)mp = x0; *((float4*)mp + 1) = x1;
  }
}

// ---------------- fused forward solve step k ----------------
// grid (4, 32-k). Every block computes Xloc = U_k * S_k(btile) redundantly.
// d==0: writes Xloc to X[k]. d>0: S_{k+d} -= L_{k+d,k} * Xloc.
__global__ __launch_bounds__(256) void k_fsolve(float* __restrict__ S,
                                                float* __restrict__ X,
                                                const float* __restrict__ M,
                                                const float* __restrict__ UTk,
                                                int k0) {
  __shared__ float Xl[NB][LSTR];
  __shared__ float Aa[16][TSTR];
  __shared__ float Bb[16][LSTR];
  int tid = threadIdx.x;
  int b0 = blockIdx.x * NB;
  int d = blockIdx.y;
  int i0g = k0 + d * NB;
  int ii = (tid >> 4) * 8, bl = (tid & 15) * 8;
  float acc[8][8] = {};
  for (int tch = 0; tch < NB; tch += 16) {
    for (int idx = tid; idx < 512; idx += 256) {
      int t = idx >> 5, f = idx & 31;
      *(float4*)&Aa[t][4 * f] = *(const float4*)(UTk + (size_t)(tch + t) * NB + 4 * f);
      *(float4*)&Bb[t][4 * f] = *(const float4*)(S + (size_t)(k0 + tch + t) * NRHS + b0 + 4 * f);
    }
    __syncthreads();
#pragma unroll 4
    for (int t = 0; t < 16; ++t) {
      float4 u0 = *(const float4*)&Aa[t][ii];
      float4 u1 = *(const float4*)&Aa[t][ii + 4];
      float4 r0v = *(const float4*)&Bb[t][bl];
      float4 r1v = *(const float4*)&Bb[t][bl + 4];
      float uv[8] = {u0.x, u0.y, u0.z, u0.w, u1.x, u1.y, u1.z, u1.w};
      float rv[8] = {r0v.x, r0v.y, r0v.z, r0v.w, r1v.x, r1v.y, r1v.z, r1v.w};
#pragma unroll
      for (int q = 0; q < 8; ++q)
#pragma unroll
        for (int w = 0; w < 8; ++w) acc[q][w] += uv[q] * rv[w];
    }
    __syncthreads();
  }
  if (d == 0) {
    for (int q = 0; q < 8; ++q) {
      float* xp = X + (size_t)(k0 + ii + q) * NRHS + b0 + bl;
      float4 x0 = {acc[q][0], acc[q][1], acc[q][2], acc[q][3]};
      float4 x1 = {acc[q][4], acc[q][5], acc[q][6], acc[q][7]};
      *(float4*)xp = x0; *((float4*)xp + 1) = x1;
    }
    return;
  }
  for (int q = 0; q < 8; ++q) {
    float4 x0 = {acc[q][0], acc[q][1], acc[q][2], acc[q][3]};
    float4 x1 = {acc[q][4], acc[q][5], acc[q][6], acc[q][7]};
    *(float4*)&Xl[ii + q][bl] = x0; *(float4*)&Xl[ii + q][bl + 4] = x1;
  }
  __syncthreads();
  float acc2[8][8] = {};
  for (int tch = 0; tch < NB; tch += 16) {
    for (int idx = tid; idx < 512; idx += 256) {
      int r = idx >> 2, q = idx & 3;
      const float4 v = *(const float4*)(M + (size_t)(i0g + r) * N + k0 + tch + 4 * q);
      Aa[4 * q + 0][r] = v.x; Aa[4 * q + 1][r] = v.y;
      Aa[4 * q + 2][r] = v.z; Aa[4 * q + 3][r] = v.w;
    }
    __syncthreads();
#pragma unroll 4
    for (int t = 0; t < 16; ++t) {
      float4 a0 = *(const float4*)&Aa[t][ii];
      float4 a1 = *(const float4*)&Aa[t][ii + 4];
      float4 b0v = *(const float4*)&Xl[tch + t][bl];
      float4 b1v = *(const float4*)&Xl[tch + t][bl + 4];
      float av[8] = {a0.x, a0.y, a0.z, a0.w, a1.x, a1.y, a1.z, a1.w};
      float bv[8] = {b0v.x, b0v.y, b0v.z, b0v.w, b1v.x, b1v.y, b1v.z, b1v.w};
#pragma unroll
      for (int q = 0; q < 8; ++q)
#pragma unroll
        for (int w = 0; w < 8; ++w) acc2[q][w] += av[q] * bv[w];
    }
    __syncthreads();
  }
  for (int q = 0; q < 8; ++q) {
    float* sp = S + (size_t)(i0g + ii + q) * NRHS + b0 + bl;
    float4 x0 = *(float4*)sp, x1 = *((float4*)sp + 1);
    x0.x -= acc2[q][0]; x0.y -= acc2[q][1]; x0.z -= acc2[q][2]; x0.w -= acc2[q][3];
    x1.x -= acc2[q][4]; x1.y -= acc2[q][5]; x1.z -= acc2[q][6]; x1.w -= acc2[q][7];
    *(float4*)sp = x0; *((float4*)sp + 1) = x1;
  }
}

// ---------------- fused backward solve step k (descending) ----------------
// grid (4, k+1). Every block computes Zloc = U_k^T * X[k](btile).
// d==0: writes Zloc to S[k] (final Z). d>0: X_{k-d} -= L_{k,k-d}^T * Zloc.
__global__ __launch_bounds__(256) void k_bsolve(float* __restrict__ X,
                                                float* __restrict__ S,
                                                const float* __restrict__ M,
                                                const float* __restrict__ Uk,
                                                int k0) {
  __shared__ float Xl[NB][LSTR];
  __shared__ float Aa[16][TSTR];
  __shared__ float Bb[16][LSTR];
  int tid = threadIdx.x;
  int b0 = blockIdx.x * NB;
  int d = blockIdx.y;
  int i0g = k0 - d * NB;
  int ii = (tid >> 4) * 8, bl = (tid & 15) * 8;
  float acc[8][8] = {};
  for (int tch = 0; tch < NB; tch += 16) {
    for (int idx = tid; idx < 512; idx += 256) {
      int t = idx >> 5, f = idx & 31;
      *(float4*)&Aa[t][4 * f] = *(const float4*)(Uk + (size_t)(tch + t) * NB + 4 * f);
      *(float4*)&Bb[t][4 * f] = *(const float4*)(X + (size_t)(k0 + tch + t) * NRHS + b0 + 4 * f);
    }
    __syncthreads();
#pragma unroll 4
    for (int t = 0; t < 16; ++t) {
      float4 u0 = *(const float4*)&Aa[t][ii];     // U[tch+t][ii..] = (U^T) fragment
      float4 u1 = *(const float4*)&Aa[t][ii + 4];
      float4 r0v = *(const float4*)&Bb[t][bl];
      float4 r1v = *(const float4*)&Bb[t][bl + 4];
      float uv[8] = {u0.x, u0.y, u0.z, u0.w, u1.x, u1.y, u1.z, u1.w};
      float rv[8] = {r0v.x, r0v.y, r0v.z, r0v.w, r1v.x, r1v.y, r1v.z, r1v.w};
#pragma unroll
      for (int q = 0; q < 8; ++q)
#pragma unroll
        for (int w = 0; w < 8; ++w) acc[q][w] += uv[q] * rv[w];
    }
    __syncthreads();
  }
  if (d == 0) {
    for (int q = 0; q < 8; ++q) {
      float* sp = S + (size_t)(k0 + ii + q) * NRHS + b0 + bl;
      float4 x0 = {acc[q][0], acc[q][1], acc[q][2], acc[q][3]};
      float4 x1 = {acc[q][4], acc[q][5], acc[q][6], acc[q][7]};
      *(float4*)sp = x0; *((float4*)sp + 1) = x1;
    }
    return;
  }
  for (int q = 0; q < 8; ++q) {
    float4 x0 = {acc[q][0], acc[q][1], acc[q][2], acc[q][3]};
    float4 x1 = {acc[q][4], acc[q][5], acc[q][6], acc[q][7]};
    *(float4*)&Xl[ii + q][bl] = x0; *(float4*)&Xl[ii + q][bl + 4] = x1;
  }
  __syncthreads();
  float acc2[8][8] = {};
  for (int tch = 0; tch < NB; tch += 16) {
    for (int idx = tid; idx < 512; idx += 256) {
      int t = idx >> 5, f = idx & 31;
      *(float4*)&Aa[t][4 * f] = *(const float4*)(M + (size_t)(k0 + tch + t) * N + i0g + 4 * f);
    }
    __syncthreads();
#pragma unroll 4
    for (int t = 0; t < 16; ++t) {
      float4 a0 = *(const float4*)&Aa[t][ii];     // L[k0+t][i0g+ii..] = L^T fragment
      float4 a1 = *(const float4*)&Aa[t][ii + 4];
      float4 b0v = *(const float4*)&Xl[tch + t][bl];
      float4 b1v = *(const float4*)&Xl[tch + t][bl + 4];
      float av[8] = {a0.x, a0.y, a0.z, a0.w, a1.x, a1.y, a1.z, a1.w};
      float bv[8] = {b0v.x, b0v.y, b0v.z, b0v.w, b1v.x, b1v.y, b1v.z, b1v.w};
#pragma unroll
      for (int q = 0; q < 8; ++q)
#pragma unroll
        for (int w = 0; w < 8; ++w) acc2[q][w] += av[q] * bv[w];
    }
    __syncthreads();
  }
  for (int q = 0; q < 8; ++q) {
    float* xp = X + (size_t)(i0g + ii + q) * NRHS + b0 + bl;
    float4 x0 = *(float4*)xp, x1 = *((float4*)xp + 1);
    x0.x -= acc2[q][0]; x0.y -= acc2[q][1]; x0.z -= acc2[q][2]; x0.w -= acc2[q][3];
    x1.x -= acc2[q][4]; x1.y -= acc2[q][5]; x1.z -= acc2[q][6]; x1.w -= acc2[q][7];
    *(float4*)xp = x0; *((float4*)xp + 1) = x1;
  }
}

// ---------------- denom + normalize + transpose to output ----------------
__global__ __launch_bounds__(256) void k_final(const float* __restrict__ S,
                                               const float* __restrict__ K,
                                               const float* __restrict__ a_ptr,
                                               float* __restrict__ out) {
  __shared__ float red[256];
  int b = blockIdx.x, tid = threadIdx.x;
  float s = 0.0f;
  for (int i = tid; i < N; i += 256) s += S[(size_t)i * NRHS + b] * K[(size_t)b * N + i];
  red[tid] = s; __syncthreads();
  for (int w = 128; w > 0; w >>= 1) { if (tid < w) red[tid] += red[tid + w]; __syncthreads(); }
  float inv = 1.0f / (a_ptr[0] * red[0]);
  for (int i = tid; i < N; i += 256) out[(size_t)b * N + i] = S[(size_t)i * NRHS + b] * inv;
}

extern "C" void kernel_launch(void* const* d_in, const int* in_sizes, int n_in,
                              void* d_out, int out_size, void* d_ws, size_t ws_size,
                              hipStream_t stream) {
  const float* Kb    = (const float*)d_in[0];
  const float* a     = (const float*)d_in[1];
  const float* exc   = (const float*)d_in[2];
  const float* imp   = (const float*)d_in[3];
  const float* Phi   = (const float*)d_in[4];
  const float* gamma = (const float*)d_in[5];
  float* out = (float*)d_out;

  float* M  = (float*)d_ws;                        // n*n            (64 MiB)
  float* S  = M + (size_t)N * N;                   // n*NRHS         (8 MiB)
  float* X  = S + (size_t)N * NRHS;                // n*NRHS         (8 MiB)
  float* U  = X + (size_t)N * NRHS;                // 32 * 128*128   (2 MiB)
  float* UT = U + (size_t)32 * NB * NB;            // 32 * 128*128   (2 MiB)
  float* c  = UT + (size_t)32 * NB * NB;           // scalars

  k_scalars<<<1, 256, 0, stream>>>(imp, exc, gamma, c);
  k_build_M<<<N * N / 1024, 256, 0, stream>>>(Phi, c, M);
  k_transpose<<<dim3(N / 32, NRHS / 32), 256, 0, stream>>>(Kb, S);

  for (int k = 0; k < 32; ++k) {
    int k0 = k * NB;
    float* Uk  = U  + (size_t)k * NB * NB;
    float* UTk = UT + (size_t)k * NB * NB;
    k_potrf_inv<<<1, 1024, 0, stream>>>(M, Uk, UTk, k0);
    int Tk = 31 - k;
    if (Tk > 0) {
      k_trsm<<<Tk, 256, 0, stream>>>(M, UTk, k0);
      k_syrk<<<dim3(Tk, Tk), 256, 0, stream>>>(M, k0);
    }
  }
  for (int k = 0; k < 32; ++k)
    k_fsolve<<<dim3(NRHS / NB, 32 - k), 256, 0, stream>>>(S, X, M, UT + (size_t)k * NB * NB, k * NB);
  for (int k = 31; k >= 0; --k)
    k_bsolve<<<dim3(NRHS / NB, k + 1), 256, 0, stream>>>(X, S, M, U + (size_t)k * NB * NB, k * NB);
  k_final<<<NRHS, 256, 0, stream>>>(S, Kb, a, out);
}

// Round 4
// 8919.326 us; speedup vs baseline: 1.4008x; 1.0078x over previous
//
#include <hip/hip_runtime.h>

// OptNet KKT layer: out = normalize(M^{-1} K^T), M = c1*Phi + c2*I (SPD, n=4096, 512 RHS).
// Blocked fp32 Cholesky. potrf+L^{-1} fused, 256 threads launch_bounds(256,1) so the
// register-resident 32x32 corners do NOT spill. Solve steps: 64-wide RHS tiles, 48KB LDS.

#define N    4096
#define NRHS 512
#define NB   128
#define LSTR 132   // padded LDS row stride for 128-wide rows
#define TSTR 136   // padded LDS row stride for t-major staging
#define BSTR 68    // padded LDS row stride for 64-wide RHS tiles

// ---------------- scalars: c1 = (||imp||^2+||exc||^2)/512, c2 = gamma/512 ----------------
__global__ __launch_bounds__(256) void k_scalars(const float* __restrict__ imp,
                                                 const float* __restrict__ exc,
                                                 const float* __restrict__ gamma,
                                                 float* __restrict__ c) {
  __shared__ float red[256];
  int tid = threadIdx.x;
  float s = 0.0f;
  for (int i = tid; i < 1024; i += 256) { float x = imp[i], y = exc[i]; s += x * x + y * y; }
  red[tid] = s; __syncthreads();
  for (int w = 128; w > 0; w >>= 1) { if (tid < w) red[tid] += red[tid + w]; __syncthreads(); }
  if (tid == 0) { c[0] = red[0] / 512.0f; c[1] = gamma[0] / 512.0f; }
}

// ---------------- M = c1*Phi + c2*I ----------------
__global__ __launch_bounds__(256) void k_build_M(const float* __restrict__ Phi,
                                                 const float* __restrict__ c,
                                                 float* __restrict__ M) {
  int idx = blockIdx.x * 256 + threadIdx.x;
  int base = idx * 4;
  float4 p = *(const float4*)(Phi + base);
  float c1 = c[0], c2 = c[1];
  float4 m;
  m.x = c1 * p.x; m.y = c1 * p.y; m.z = c1 * p.z; m.w = c1 * p.w;
  int r = base >> 12, c0 = base & (N - 1);
  if (r == c0)     m.x += c2;
  if (r == c0 + 1) m.y += c2;
  if (r == c0 + 2) m.z += c2;
  if (r == c0 + 3) m.w += c2;
  *(float4*)(M + base) = m;
}

// ---------------- S[i][b] = K[b][i] ----------------
__global__ __launch_bounds__(256) void k_transpose(const float* __restrict__ K,
                                                   float* __restrict__ S) {
  __shared__ float t[32][33];
  int bi = blockIdx.x, bb = blockIdx.y;
  int tx = threadIdx.x & 31, ty = threadIdx.x >> 5;
  for (int r = 0; r < 4; ++r)
    t[ty + 8 * r][tx] = K[(size_t)(bb * 32 + ty + 8 * r) * N + bi * 32 + tx];
  __syncthreads();
  for (int r = 0; r < 4; ++r)
    S[(size_t)(bi * 32 + ty + 8 * r) * NRHS + bb * 32 + tx] = t[tx][ty + 8 * r];
}

// ---------------- fused: Cholesky of 128x128 diag block + U = L^{-1} (and UT) ----------------
// One block, 256 threads, launch_bounds(256,1) => up to 512 VGPR/lane, no spill for the
// register-resident 32x32 corner factorization/inversion on wave 0.
__global__ __launch_bounds__(256, 1) void k_potrf_inv(float* __restrict__ M,
                                                      float* __restrict__ U,
                                                      float* __restrict__ UT,
                                                      int k0) {
  __shared__ float Lb[NB][LSTR];
  __shared__ float Us[NB][LSTR];
  __shared__ float Tl[3][32][33];
  int tid = threadIdx.x;
  for (int idx = tid; idx < NB * 32; idx += 256) {
    int i = idx >> 5, f = idx & 31;
    *(float4*)&Lb[i][4 * f] = *(const float4*)(M + (size_t)(k0 + i) * N + k0 + 4 * f);
    *(float4*)&Us[i][4 * f] = make_float4(0.f, 0.f, 0.f, 0.f);
  }
  __syncthreads();
  int l = tid;
  for (int p = 0; p < 4; ++p) {
    int b0 = 32 * p;
    if (tid < 32) {
      float r[32];
#pragma unroll
      for (int t = 0; t < 32; ++t) r[t] = Lb[b0 + l][b0 + t];
#pragma unroll
      for (int j = 0; j < 32; ++j) {
        float ajj = __shfl(r[j], j);
        float sq = sqrtf(ajj);
        float inv = 1.0f / sq;
        if (l == j) r[j] = sq;
        else if (l > j) r[j] *= inv;
#pragma unroll
        for (int t = j + 1; t < 32; ++t) {
          float Ltj = __shfl(r[j], t);
          if (l >= t) r[t] -= r[j] * Ltj;
        }
      }
#pragma unroll
      for (int t = 0; t < 32; ++t) if (t <= l) Lb[b0 + l][b0 + t] = r[t];
      // corner inverse V = L_corner^{-1}: lane l computes column l
      float x[32];
#pragma unroll
      for (int i = 0; i < 32; ++i) {
        float s = 0.0f;
#pragma unroll
        for (int t = 0; t < i; ++t) {
          float Lit = __shfl(r[t], i);
          s += Lit * x[t];
        }
        float di = __shfl(r[i], i);
        float dl = (l == i) ? 1.0f : 0.0f;
        x[i] = (dl - s) / di;
      }
#pragma unroll
      for (int i = 0; i < 32; ++i) Us[b0 + i][b0 + l] = x[i];
    }
    __syncthreads();
    int base = b0 + 32;
    int nbl = NB - base;
    if (nbl > 0) {
      // strip TRSM: Lb[base+r][b0+c] = sum_t A[base+r][b0+t] * V[c][t]
      int cnt = nbl * 32;
      float pv[12];
#pragma unroll
      for (int e = 0; e < 12; ++e) {
        int idx = tid + e * 256;
        if (idx < cnt) {
          int r = idx >> 5, cc = idx & 31;
          float s = 0.0f;
#pragma unroll
          for (int t = 0; t < 32; ++t)
            s += Lb[base + r][b0 + t] * Us[b0 + cc][b0 + t];
          pv[e] = s;
        }
      }
      __syncthreads();
#pragma unroll
      for (int e = 0; e < 12; ++e) {
        int idx = tid + e * 256;
        if (idx < cnt) {
          int r = idx >> 5, cc = idx & 31;
          Lb[base + r][b0 + cc] = pv[e];
        }
      }
      __syncthreads();
      // rank-32 trailing update (lower incl diag)
      int tot = nbl * nbl;
      for (int idx = tid; idx < tot; idx += 256) {
        int i = idx / nbl, j = idx - i * nbl;
        if (j <= i) {
          float4 a0 = *(const float4*)&Lb[base + i][b0];
          float4 a1 = *(const float4*)&Lb[base + i][b0 + 4];
          float4 a2 = *(const float4*)&Lb[base + i][b0 + 8];
          float4 a3 = *(const float4*)&Lb[base + i][b0 + 12];
          float4 a4 = *(const float4*)&Lb[base + i][b0 + 16];
          float4 a5 = *(const float4*)&Lb[base + i][b0 + 20];
          float4 a6 = *(const float4*)&Lb[base + i][b0 + 24];
          float4 a7 = *(const float4*)&Lb[base + i][b0 + 28];
          float4 b0v = *(const float4*)&Lb[base + j][b0];
          float4 b1v = *(const float4*)&Lb[base + j][b0 + 4];
          float4 b2v = *(const float4*)&Lb[base + j][b0 + 8];
          float4 b3v = *(const float4*)&Lb[base + j][b0 + 12];
          float4 b4v = *(const float4*)&Lb[base + j][b0 + 16];
          float4 b5v = *(const float4*)&Lb[base + j][b0 + 20];
          float4 b6v = *(const float4*)&Lb[base + j][b0 + 24];
          float4 b7v = *(const float4*)&Lb[base + j][b0 + 28];
          float s = a0.x*b0v.x + a0.y*b0v.y + a0.z*b0v.z + a0.w*b0v.w
                  + a1.x*b1v.x + a1.y*b1v.y + a1.z*b1v.z + a1.w*b1v.w
                  + a2.x*b2v.x + a2.y*b2v.y + a2.z*b2v.z + a2.w*b2v.w
                  + a3.x*b3v.x + a3.y*b3v.y + a3.z*b3v.z + a3.w*b3v.w
                  + a4.x*b4v.x + a4.y*b4v.y + a4.z*b4v.z + a4.w*b4v.w
                  + a5.x*b5v.x + a5.y*b5v.y + a5.z*b5v.z + a5.w*b5v.w
                  + a6.x*b6v.x + a6.y*b6v.y + a6.z*b6v.z + a6.w*b6v.w
                  + a7.x*b7v.x + a7.y*b7v.y + a7.z*b7v.z + a7.w*b7v.w;
          Lb[base + i][base + j] -= s;
        }
      }
      __syncthreads();
    }
  }
  // assemble off-diagonal blocks of U = L^{-1}: U_ij = -V_i * (sum_{t=32j..32i-1} L_it U_tj)
  for (int d = 1; d <= 3; ++d) {
    int nb = 4 - d;
    for (int blk = 0; blk < nb; ++blk) {
      int bi = blk + d, bj = blk;
#pragma unroll
      for (int e = 0; e < 4; ++e) {
        int el = tid + 256 * e;
        int rr = el >> 5, cc = el & 31;
        float s = 0.0f;
        for (int t = 32 * bj; t < 32 * bi; ++t)
          s += Lb[32 * bi + rr][t] * Us[t][32 * bj + cc];
        Tl[blk][rr][cc] = s;
      }
    }
    __syncthreads();
    for (int blk = 0; blk < nb; ++blk) {
      int bi = blk + d, bj = blk;
#pragma unroll
      for (int e = 0; e < 4; ++e) {
        int el = tid + 256 * e;
        int rr = el >> 5, cc = el & 31;
        float s = 0.0f;
#pragma unroll
        for (int t = 0; t < 32; ++t)
          s += Us[32 * bi + rr][32 * bi + t] * Tl[blk][t][cc];
        Us[32 * bi + rr][32 * bj + cc] = -s;
      }
    }
    __syncthreads();
  }
  for (int idx = tid; idx < NB * 32; idx += 256) {
    int i = idx >> 5, f = idx & 31;
    *(float4*)(M + (size_t)(k0 + i) * N + k0 + 4 * f) = *(const float4*)&Lb[i][4 * f];
    *(float4*)(U + (size_t)i * NB + 4 * f) = *(const float4*)&Us[i][4 * f];
    float4 v;
    v.x = Us[4 * f + 0][i]; v.y = Us[4 * f + 1][i];
    v.z = Us[4 * f + 2][i]; v.w = Us[4 * f + 3][i];
    *(float4*)(UT + (size_t)i * NB + 4 * f) = v;
  }
}

// ---------------- panel TRSM as GEMM: P := P_old * U^T ----------------
__global__ __launch_bounds__(256) void k_trsm(float* __restrict__ M,
                                              const float* __restrict__ UT, int k0) {
  __shared__ float Ut[NB][LSTR];
  __shared__ float At[16][TSTR];
  int tid = threadIdx.x;
  int r0 = k0 + NB + blockIdx.x * NB;
  for (int idx = tid; idx < NB * 32; idx += 256) {
    int t = idx >> 5, f = idx & 31;
    *(float4*)&Ut[t][4 * f] = *(const float4*)(UT + (size_t)t * NB + 4 * f);
  }
  int i0 = (tid >> 4) * 8, j0 = (tid & 15) * 8;
  float acc[8][8] = {};
  for (int tch = 0; tch < NB; tch += 16) {
    for (int idx = tid; idx < 512; idx += 256) {
      int r = idx >> 2, q = idx & 3;
      const float4 v = *(const float4*)(M + (size_t)(r0 + r) * N + k0 + tch + 4 * q);
      At[4 * q + 0][r] = v.x; At[4 * q + 1][r] = v.y;
      At[4 * q + 2][r] = v.z; At[4 * q + 3][r] = v.w;
    }
    __syncthreads();
#pragma unroll 4
    for (int t = 0; t < 16; ++t) {
      float4 a0 = *(const float4*)&At[t][i0];
      float4 a1 = *(const float4*)&At[t][i0 + 4];
      float4 u0 = *(const float4*)&Ut[tch + t][j0];
      float4 u1 = *(const float4*)&Ut[tch + t][j0 + 4];
      float av[8] = {a0.x, a0.y, a0.z, a0.w, a1.x, a1.y, a1.z, a1.w};
      float uv[8] = {u0.x, u0.y, u0.z, u0.w, u1.x, u1.y, u1.z, u1.w};
#pragma unroll
      for (int q = 0; q < 8; ++q)
#pragma unroll
        for (int w = 0; w < 8; ++w) acc[q][w] += av[q] * uv[w];
    }
    __syncthreads();
  }
  for (int q = 0; q < 8; ++q) {
    float* mp = M + (size_t)(r0 + i0 + q) * N + k0 + j0;
    float4 x0 = {acc[q][0], acc[q][1], acc[q][2], acc[q][3]};
    float4 x1 = {acc[q][4], acc[q][5], acc[q][6], acc[q][7]};
    *(float4*)mp = x0; *((float4*)mp + 1) = x1;
  }
}

// ---------------- SYRK trailing update: C -= P P^T (lower tiles) ----------------
__global__ __launch_bounds__(256) void k_syrk(float* __restrict__ M, int k0) {
  int br = blockIdx.y, bc = blockIdx.x;
  if (bc > br) return;
  int t0 = k0 + NB;
  int r0 = t0 + br * NB, c0 = t0 + bc * NB;
  __shared__ float Pa[16][TSTR], Pb[16][TSTR];
  int tid = threadIdx.x;
  int rr = (tid >> 4) * 8, cc = (tid & 15) * 8;
  float acc[8][8] = {};
  for (int tch = 0; tch < NB; tch += 16) {
    for (int idx = tid; idx < 1024; idx += 256) {
      int sel = idx >> 9, id2 = idx & 511;
      int r = id2 >> 2, q = id2 & 3;
      const float4 v = *(const float4*)(M + (size_t)((sel ? c0 : r0) + r) * N + k0 + tch + 4 * q);
      float* dst = sel ? &Pb[0][0] : &Pa[0][0];
      dst[(4 * q + 0) * TSTR + r] = v.x;
      dst[(4 * q + 1) * TSTR + r] = v.y;
      dst[(4 * q + 2) * TSTR + r] = v.z;
      dst[(4 * q + 3) * TSTR + r] = v.w;
    }
    __syncthreads();
#pragma unroll 4
    for (int t = 0; t < 16; ++t) {
      float4 a0 = *(const float4*)&Pa[t][rr];
      float4 a1 = *(const float4*)&Pa[t][rr + 4];
      float4 b0 = *(const float4*)&Pb[t][cc];
      float4 b1 = *(const float4*)&Pb[t][cc + 4];
      float av[8] = {a0.x, a0.y, a0.z, a0.w, a1.x, a1.y, a1.z, a1.w};
      float bv[8] = {b0.x, b0.y, b0.z, b0.w, b1.x, b1.y, b1.z, b1.w};
#pragma unroll
      for (int q = 0; q < 8; ++q)
#pragma unroll
        for (int w = 0; w < 8; ++w) acc[q][w] += av[q] * bv[w];
    }
    __syncthreads();
  }
  for (int q = 0; q < 8; ++q) {
    float* mp = M + (size_t)(r0 + rr + q) * N + c0 + cc;
    float4 x0 = *(float4*)mp, x1 = *((float4*)mp + 1);
    x0.x -= acc[q][0]; x0.y -= acc[q][1]; x0.z -= acc[q][2]; x0.w -= acc[q][3];
    x1.x -= acc[q][4]; x1.y -= acc[q][5]; x1.z -= acc[q][6]; x1.w -= acc[q][7];
    *(float4*)mp = x0; *((float4*)mp + 1) = x1;
  }
}

// ---------------- fused forward solve step k ----------------
// grid (8, 32-k), 64-wide RHS tiles. Every block computes Xloc = U_k * S_k(btile).
// d==0: Xloc -> X[k]. d>0: S_{k+d} -= L_{k+d,k} * Xloc.
__global__ __launch_bounds__(256) void k_fsolve(float* __restrict__ S,
                                                float* __restrict__ X,
                                                const float* __restrict__ M,
                                                const float* __restrict__ UTk,
                                                int k0) {
  __shared__ float Xl[NB][BSTR];
  __shared__ float Aa[16][TSTR];
  __shared__ float Bb[16][BSTR];
  int tid = threadIdx.x;
  int b0 = blockIdx.x * 64;
  int d = blockIdx.y;
  int i0g = k0 + d * NB;
  int ii = (tid >> 3) * 4, bl = (tid & 7) * 8;
  float acc[4][8] = {};
  for (int tch = 0; tch < NB; tch += 16) {
    for (int idx = tid; idx < 512; idx += 256) {
      int t = idx >> 5, f = idx & 31;
      *(float4*)&Aa[t][4 * f] = *(const float4*)(UTk + (size_t)(tch + t) * NB + 4 * f);
    }
    {
      int t = tid >> 4, f = tid & 15;
      *(float4*)&Bb[t][4 * f] = *(const float4*)(S + (size_t)(k0 + tch + t) * NRHS + b0 + 4 * f);
    }
    __syncthreads();
#pragma unroll 4
    for (int t = 0; t < 16; ++t) {
      float4 a0 = *(const float4*)&Aa[t][ii];
      float4 b0v = *(const float4*)&Bb[t][bl];
      float4 b1v = *(const float4*)&Bb[t][bl + 4];
      float av[4] = {a0.x, a0.y, a0.z, a0.w};
      float bv[8] = {b0v.x, b0v.y, b0v.z, b0v.w, b1v.x, b1v.y, b1v.z, b1v.w};
#pragma unroll
      for (int q = 0; q < 4; ++q)
#pragma unroll
        for (int w = 0; w < 8; ++w) acc[q][w] += av[q] * bv[w];
    }
    __syncthreads();
  }
  if (d == 0) {
    for (int q = 0; q < 4; ++q) {
      float* xp = X + (size_t)(k0 + ii + q) * NRHS + b0 + bl;
      float4 x0 = {acc[q][0], acc[q][1], acc[q][2], acc[q][3]};
      float4 x1 = {acc[q][4], acc[q][5], acc[q][6], acc[q][7]};
      *(float4*)xp = x0; *((float4*)xp + 1) = x1;
    }
    return;
  }
  for (int q = 0; q < 4; ++q) {
    float4 x0 = {acc[q][0], acc[q][1], acc[q][2], acc[q][3]};
    float4 x1 = {acc[q][4], acc[q][5], acc[q][6], acc[q][7]};
    *(float4*)&Xl[ii + q][bl] = x0; *(float4*)&Xl[ii + q][bl + 4] = x1;
  }
  __syncthreads();
  float acc2[4][8] = {};
  for (int tch = 0; tch < NB; tch += 16) {
    for (int idx = tid; idx < 512; idx += 256) {
      int r = idx >> 2, q = idx & 3;
      const float4 v = *(const float4*)(M + (size_t)(i0g + r) * N + k0 + tch + 4 * q);
      Aa[4 * q + 0][r] = v.x; Aa[4 * q + 1][r] = v.y;
      Aa[4 * q + 2][r] = v.z; Aa[4 * q + 3][r] = v.w;
    }
    __syncthreads();
#pragma unroll 4
    for (int t = 0; t < 16; ++t) {
      float4 a0 = *(const float4*)&Aa[t][ii];
      float4 b0v = *(const float4*)&Xl[tch + t][bl];
      float4 b1v = *(const float4*)&Xl[tch + t][bl + 4];
      float av[4] = {a0.x, a0.y, a0.z, a0.w};
      float bv[8] = {b0v.x, b0v.y, b0v.z, b0v.w, b1v.x, b1v.y, b1v.z, b1v.w};
#pragma unroll
      for (int q = 0; q < 4; ++q)
#pragma unroll
        for (int w = 0; w < 8; ++w) acc2[q][w] += av[q] * bv[w];
    }
    __syncthreads();
  }
  for (int q = 0; q < 4; ++q) {
    float* sp = S + (size_t)(i0g + ii + q) * NRHS + b0 + bl;
    float4 x0 = *(float4*)sp, x1 = *((float4*)sp + 1);
    x0.x -= acc2[q][0]; x0.y -= acc2[q][1]; x0.z -= acc2[q][2]; x0.w -= acc2[q][3];
    x1.x -= acc2[q][4]; x1.y -= acc2[q][5]; x1.z -= acc2[q][6]; x1.w -= acc2[q][7];
    *(float4*)sp = x0; *((float4*)sp + 1) = x1;
  }
}

// ---------------- fused backward solve step k (descending) ----------------
// grid (8, k+1). Zloc = U_k^T * X[k](btile). d==0: -> S[k]. d>0: X_{k-d} -= L^T * Zloc.
__global__ __launch_bounds__(256) void k_bsolve(float* __restrict__ X,
                                                float* __restrict__ S,
                                                const float* __restrict__ M,
                                                const float* __restrict__ Uk,
                                                int k0) {
  __shared__ float Xl[NB][BSTR];
  __shared__ float Aa[16][TSTR];
  __shared__ float Bb[16][BSTR];
  int tid = threadIdx.x;
  int b0 = blockIdx.x * 64;
  int d = blockIdx.y;
  int i0g = k0 - d * NB;
  int ii = (tid >> 3) * 4, bl = (tid & 7) * 8;
  float acc[4][8] = {};
  for (int tch = 0; tch < NB; tch += 16) {
    for (int idx = tid; idx < 512; idx += 256) {
      int t = idx >> 5, f = idx & 31;
      *(float4*)&Aa[t][4 * f] = *(const float4*)(Uk + (size_t)(tch + t) * NB + 4 * f);
    }
    {
      int t = tid >> 4, f = tid & 15;
      *(float4*)&Bb[t][4 * f] = *(const float4*)(X + (size_t)(k0 + tch + t) * NRHS + b0 + 4 * f);
    }
    __syncthreads();
#pragma unroll 4
    for (int t = 0; t < 16; ++t) {
      float4 a0 = *(const float4*)&Aa[t][ii];     // Uk[tch+t][ii..] = (U^T) fragment
      float4 b0v = *(const float4*)&Bb[t][bl];
      float4 b1v = *(const float4*)&Bb[t][bl + 4];
      float av[4] = {a0.x, a0.y, a0.z, a0.w};
      float bv[8] = {b0v.x, b0v.y, b0v.z, b0v.w, b1v.x, b1v.y, b1v.z, b1v.w};
#pragma unroll
      for (int q = 0; q < 4; ++q)
#pragma unroll
        for (int w = 0; w < 8; ++w) acc[q][w] += av[q] * bv[w];
    }
    __syncthreads();
  }
  if (d == 0) {
    for (int q = 0; q < 4; ++q) {
      float* sp = S + (size_t)(k0 + ii + q) * NRHS + b0 + bl;
      float4 x0 = {acc[q][0], acc[q][1], acc[q][2], acc[q][3]};
      float4 x1 = {acc[q][4], acc[q][5], acc[q][6], acc[q][7]};
      *(float4*)sp = x0; *((float4*)sp + 1) = x1;
    }
    return;
  }
  for (int q = 0; q < 4; ++q) {
    float4 x0 = {acc[q][0], acc[q][1], acc[q][2], acc[q][3]};
    float4 x1 = {acc[q][4], acc[q][5], acc[q][6], acc[q][7]};
    *(float4*)&Xl[ii + q][bl] = x0; *(float4*)&Xl[ii + q][bl + 4] = x1;
  }
  __syncthreads();
  float acc2[4][8] = {};
  for (int tch = 0; tch < NB; tch += 16) {
    for (int idx = tid; idx < 512; idx += 256) {
      int t = idx >> 5, f = idx & 31;
      *(float4*)&Aa[t][4 * f] = *(const float4*)(M + (size_t)(k0 + tch + t) * N + i0g + 4 * f);
    }
    __syncthreads();
#pragma unroll 4
    for (int t = 0; t < 16; ++t) {
      float4 a0 = *(const float4*)&Aa[t][ii];     // L[k0+t][i0g+ii..] = L^T fragment
      float4 b0v = *(const float4*)&Xl[tch + t][bl];
      float4 b1v = *(const float4*)&Xl[tch + t][bl + 4];
      float av[4] = {a0.x, a0.y, a0.z, a0.w};
      float bv[8] = {b0v.x, b0v.y, b0v.z, b0v.w, b1v.x, b1v.y, b1v.z, b1v.w};
#pragma unroll
      for (int q = 0; q < 4; ++q)
#pragma unroll
        for (int w = 0; w < 8; ++w) acc2[q][w] += av[q] * bv[w];
    }
    __syncthreads();
  }
  for (int q = 0; q < 4; ++q) {
    float* xp = X + (size_t)(i0g + ii + q) * NRHS + b0 + bl;
    float4 x0 = *(float4*)xp, x1 = *((float4*)xp + 1);
    x0.x -= acc2[q][0]; x0.y -= acc2[q][1]; x0.z -= acc2[q][2]; x0.w -= acc2[q][3];
    x1.x -= acc2[q][4]; x1.y -= acc2[q][5]; x1.z -= acc2[q][6]; x1.w -= acc2[q][7];
    *(float4*)xp = x0; *((float4*)xp + 1) = x1;
  }
}

// ---------------- denom + normalize + transpose to output ----------------
__global__ __launch_bounds__(256) void k_final(const float* __restrict__ S,
                                               const float* __restrict__ K,
                                               const float* __restrict__ a_ptr,
                                               float* __restrict__ out) {
  __shared__ float red[256];
  int b = blockIdx.x, tid = threadIdx.x;
  float s = 0.0f;
  for (int i = tid; i < N; i += 256) s += S[(size_t)i * NRHS + b] * K[(size_t)b * N + i];
  red[tid] = s; __syncthreads();
  for (int w = 128; w > 0; w >>= 1) { if (tid < w) red[tid] += red[tid + w]; __syncthreads(); }
  float inv = 1.0f / (a_ptr[0] * red[0]);
  for (int i = tid; i < N; i += 256) out[(size_t)b * N + i] = S[(size_t)i * NRHS + b] * inv;
}

extern "C" void kernel_launch(void* const* d_in, const int* in_sizes, int n_in,
                              void* d_out, int out_size, void* d_ws, size_t ws_size,
                              hipStream_t stream) {
  const float* Kb    = (const float*)d_in[0];
  const float* a     = (const float*)d_in[1];
  const float* exc   = (const float*)d_in[2];
  const float* imp   = (const float*)d_in[3];
  const float* Phi   = (const float*)d_in[4];
  const float* gamma = (const float*)d_in[5];
  float* out = (float*)d_out;

  float* M  = (float*)d_ws;                        // n*n            (64 MiB)
  float* S  = M + (size_t)N * N;                   // n*NRHS         (8 MiB)
  float* X  = S + (size_t)N * NRHS;                // n*NRHS         (8 MiB)
  float* U  = X + (size_t)N * NRHS;                // 32 * 128*128   (2 MiB)
  float* UT = U + (size_t)32 * NB * NB;            // 32 * 128*128   (2 MiB)
  float* c  = UT + (size_t)32 * NB * NB;           // scalars

  k_scalars<<<1, 256, 0, stream>>>(imp, exc, gamma, c);
  k_build_M<<<N * N / 1024, 256, 0, stream>>>(Phi, c, M);
  k_transpose<<<dim3(N / 32, NRHS / 32), 256, 0, stream>>>(Kb, S);

  for (int k = 0; k < 32; ++k) {
    int k0 = k * NB;
    float* Uk  = U  + (size_t)k * NB * NB;
    float* UTk = UT + (size_t)k * NB * NB;
    k_potrf_inv<<<1, 256, 0, stream>>>(M, Uk, UTk, k0);
    int Tk = 31 - k;
    if (Tk > 0) {
      k_trsm<<<Tk, 256, 0, stream>>>(M, UTk, k0);
      k_syrk<<<dim3(Tk, Tk), 256, 0, stream>>>(M, k0);
    }
  }
  for (int k = 0; k < 32; ++k)
    k_fsolve<<<dim3(NRHS / 64, 32 - k), 256, 0, stream>>>(S, X, M, UT + (size_t)k * NB * NB, k * NB);
  for (int k = 31; k >= 0; --k)
    k_bsolve<<<dim3(NRHS / 64, k + 1), 256, 0, stream>>>(X, S, M, U + (size_t)k * NB * NB, k * NB);
  k_final<<<NRHS, 256, 0, stream>>>(S, Kb, a, out);
}

// Round 5
// 7276.983 us; speedup vs baseline: 1.7169x; 1.2257x over previous
//
#include <hip/hip_runtime.h>

// OptNet KKT layer: out = normalize(M^{-1} K^T), M = c1*Phi + c2*I (SPD, n=4096, 512 RHS).
// Blocked fp32 Cholesky with LOOKAHEAD: potrf(k+1) runs as block 0 of the syrk(k)
// dispatch (redundant diag update in LDS), overlapping the serial diag factorization
// with the trailing-update GEMMs. Corner inverses use LDS-broadcast (no shfl chains).

#define N    4096
#define NRHS 512
#define NB   128
#define LSTR 132   // padded LDS row stride for 128-wide rows
#define TSTR 136   // padded LDS row stride for t-major staging
#define BSTR 68    // padded LDS row stride for 64-wide RHS tiles
#define ASTR 36    // Tl row stride (16B-aligned float4 rows)

// ---------------- scalars ----------------
__global__ __launch_bounds__(256) void k_scalars(const float* __restrict__ imp,
                                                 const float* __restrict__ exc,
                                                 const float* __restrict__ gamma,
                                                 float* __restrict__ c) {
  __shared__ float red[256];
  int tid = threadIdx.x;
  float s = 0.0f;
  for (int i = tid; i < 1024; i += 256) { float x = imp[i], y = exc[i]; s += x * x + y * y; }
  red[tid] = s; __syncthreads();
  for (int w = 128; w > 0; w >>= 1) { if (tid < w) red[tid] += red[tid + w]; __syncthreads(); }
  if (tid == 0) { c[0] = red[0] / 512.0f; c[1] = gamma[0] / 512.0f; }
}

// ---------------- M = c1*Phi + c2*I ----------------
__global__ __launch_bounds__(256) void k_build_M(const float* __restrict__ Phi,
                                                 const float* __restrict__ c,
                                                 float* __restrict__ M) {
  int idx = blockIdx.x * 256 + threadIdx.x;
  int base = idx * 4;
  float4 p = *(const float4*)(Phi + base);
  float c1 = c[0], c2 = c[1];
  float4 m;
  m.x = c1 * p.x; m.y = c1 * p.y; m.z = c1 * p.z; m.w = c1 * p.w;
  int r = base >> 12, c0 = base & (N - 1);
  if (r == c0)     m.x += c2;
  if (r == c0 + 1) m.y += c2;
  if (r == c0 + 2) m.z += c2;
  if (r == c0 + 3) m.w += c2;
  *(float4*)(M + base) = m;
}

// ---------------- S[i][b] = K[b][i] ----------------
__global__ __launch_bounds__(256) void k_transpose(const float* __restrict__ K,
                                                   float* __restrict__ S) {
  __shared__ float t[32][33];
  int bi = blockIdx.x, bb = blockIdx.y;
  int tx = threadIdx.x & 31, ty = threadIdx.x >> 5;
  for (int r = 0; r < 4; ++r)
    t[ty + 8 * r][tx] = K[(size_t)(bb * 32 + ty + 8 * r) * N + bi * 32 + tx];
  __syncthreads();
  for (int r = 0; r < 4; ++r)
    S[(size_t)(bi * 32 + ty + 8 * r) * NRHS + bb * 32 + tx] = t[tx][ty + 8 * r];
}

struct SyrkSmem { float Pa[16][TSTR]; float Pb[16][TSTR]; };
struct AsmSmem  { float Tl[3][32][ASTR]; float dinv[NB]; };
union USmem { SyrkSmem s; AsmSmem a; };

// ---------------- fused syrk(k) + lookahead potrf(k+1) ----------------
// grid = T(T+1)/2 blocks, T = 32 - kdiag.  bid 0: potrf role (applies its own panel
// update to diag tile kdiag, factors, writes L/U/UT).  bid >= 1: trailing syrk tile
// (br,bc) = tri-decode(bid), origin kdiag*NB, panel cols k0.
__global__ __launch_bounds__(256, 1) void k_syrk_potrf(float* __restrict__ M,
                                                       float* __restrict__ U,
                                                       float* __restrict__ UT,
                                                       int kdiag, int k0) {
  __shared__ float Lb[NB][LSTR];
  __shared__ float Us[NB][LSTR];
  __shared__ USmem un;
  int tid = threadIdx.x;
  int bid = blockIdx.x;

  if (bid > 0) {
    // ================= syrk role =================
    int p = bid;
    int br = (int)((sqrtf(8.f * (float)p + 1.f) - 1.f) * 0.5f);
    while (((br + 1) * (br + 2)) / 2 <= p) ++br;
    while ((br * (br + 1)) / 2 > p) --br;
    int bc = p - (br * (br + 1)) / 2;
    int t0 = kdiag * NB;
    int r0 = t0 + br * NB, c0 = t0 + bc * NB;
    int rr = (tid >> 4) * 8, cc = (tid & 15) * 8;
    float acc[8][8] = {};
    for (int tch = 0; tch < NB; tch += 16) {
      for (int idx = tid; idx < 1024; idx += 256) {
        int sel = idx >> 9, id2 = idx & 511;
        int r = id2 >> 2, q = id2 & 3;
        const float4 v = *(const float4*)(M + (size_t)((sel ? c0 : r0) + r) * N + k0 + tch + 4 * q);
        float* dst = sel ? &un.s.Pb[0][0] : &un.s.Pa[0][0];
        dst[(4 * q + 0) * TSTR + r] = v.x;
        dst[(4 * q + 1) * TSTR + r] = v.y;
        dst[(4 * q + 2) * TSTR + r] = v.z;
        dst[(4 * q + 3) * TSTR + r] = v.w;
      }
      __syncthreads();
#pragma unroll 4
      for (int t = 0; t < 16; ++t) {
        float4 a0 = *(const float4*)&un.s.Pa[t][rr];
        float4 a1 = *(const float4*)&un.s.Pa[t][rr + 4];
        float4 b0 = *(const float4*)&un.s.Pb[t][cc];
        float4 b1 = *(const float4*)&un.s.Pb[t][cc + 4];
        float av[8] = {a0.x, a0.y, a0.z, a0.w, a1.x, a1.y, a1.z, a1.w};
        float bv[8] = {b0.x, b0.y, b0.z, b0.w, b1.x, b1.y, b1.z, b1.w};
#pragma unroll
        for (int q = 0; q < 8; ++q)
#pragma unroll
          for (int w = 0; w < 8; ++w) acc[q][w] += av[q] * bv[w];
      }
      __syncthreads();
    }
    for (int q = 0; q < 8; ++q) {
      float* mp = M + (size_t)(r0 + rr + q) * N + c0 + cc;
      float4 x0 = *(float4*)mp, x1 = *((float4*)mp + 1);
      x0.x -= acc[q][0]; x0.y -= acc[q][1]; x0.z -= acc[q][2]; x0.w -= acc[q][3];
      x1.x -= acc[q][4]; x1.y -= acc[q][5]; x1.z -= acc[q][6]; x1.w -= acc[q][7];
      *(float4*)mp = x0; *((float4*)mp + 1) = x1;
    }
    return;
  }

  // ================= potrf role =================
  int kr = kdiag * NB;
  int rr = (tid >> 4) * 8, cc = (tid & 15) * 8;
  float accd[8][8] = {};
  if (k0 >= 0) {  // redundant diag update: D -= P P^T, P = M[kr.., k0..]
    for (int tch = 0; tch < NB; tch += 16) {
      for (int idx = tid; idx < 512; idx += 256) {
        int r = idx >> 2, q = idx & 3;
        const float4 v = *(const float4*)(M + (size_t)(kr + r) * N + k0 + tch + 4 * q);
        un.s.Pa[4 * q + 0][r] = v.x; un.s.Pa[4 * q + 1][r] = v.y;
        un.s.Pa[4 * q + 2][r] = v.z; un.s.Pa[4 * q + 3][r] = v.w;
      }
      __syncthreads();
#pragma unroll 4
      for (int t = 0; t < 16; ++t) {
        float4 a0 = *(const float4*)&un.s.Pa[t][rr];
        float4 a1 = *(const float4*)&un.s.Pa[t][rr + 4];
        float4 b0 = *(const float4*)&un.s.Pa[t][cc];
        float4 b1 = *(const float4*)&un.s.Pa[t][cc + 4];
        float av[8] = {a0.x, a0.y, a0.z, a0.w, a1.x, a1.y, a1.z, a1.w};
        float bv[8] = {b0.x, b0.y, b0.z, b0.w, b1.x, b1.y, b1.z, b1.w};
#pragma unroll
        for (int q = 0; q < 8; ++q)
#pragma unroll
          for (int w = 0; w < 8; ++w) accd[q][w] += av[q] * bv[w];
      }
      __syncthreads();
    }
  }
  for (int idx = tid; idx < NB * 32; idx += 256) {
    int i = idx >> 5, f = idx & 31;
    *(float4*)&Lb[i][4 * f] = *(const float4*)(M + (size_t)(kr + i) * N + kr + 4 * f);
    *(float4*)&Us[i][4 * f] = make_float4(0.f, 0.f, 0.f, 0.f);
  }
  __syncthreads();
  if (k0 >= 0) {
    for (int q = 0; q < 8; ++q)
      for (int w = 0; w < 8; ++w)
        Lb[rr + q][cc + w] -= accd[q][w];
  }
  __syncthreads();

  int l = tid;
#pragma unroll 1
  for (int p = 0; p < 4; ++p) {
    int b0 = 32 * p;
    // ---- corner factor (registers + shfl), also store 1/diag ----
    if (tid < 32) {
      float r[32];
#pragma unroll
      for (int t = 0; t < 32; ++t) r[t] = Lb[b0 + l][b0 + t];
#pragma unroll
      for (int j = 0; j < 32; ++j) {
        float ajj = __shfl(r[j], j);
        float sq = sqrtf(ajj);
        float inv = 1.0f / sq;
        if (l == 0) un.a.dinv[b0 + j] = inv;
        if (l == j) r[j] = sq;
        else if (l > j) r[j] *= inv;
#pragma unroll
        for (int t = j + 1; t < 32; ++t) {
          float Ltj = __shfl(r[j], t);
          if (l >= t) r[t] -= r[j] * Ltj;
        }
      }
#pragma unroll
      for (int t = 0; t < 32; ++t) if (t <= l) Lb[b0 + l][b0 + t] = r[t];
    }
    __syncthreads();
    // ---- corner inverse via LDS broadcast: lane l = column l of V ----
    if (tid < 32) {
      float x[32];
#pragma unroll
      for (int i = 0; i < 32; ++i) {
        float s = (l == i) ? 1.0f : 0.0f;
#pragma unroll
        for (int t = 0; t < i; ++t) s -= Lb[b0 + i][b0 + t] * x[t];
        x[i] = s * un.a.dinv[b0 + i];
      }
#pragma unroll
      for (int i = 0; i < 32; ++i) Us[b0 + i][b0 + l] = x[i];
    }
    __syncthreads();
    int base = b0 + 32;
    int nbl = NB - base;
    if (nbl > 0) {
      // ---- strip TRSM: rows below corner x V^T ----
      int cnt = nbl * 32;
      float pv[12];
#pragma unroll
      for (int e = 0; e < 12; ++e) {
        int idx = tid + e * 256;
        if (idx < cnt) {
          int r2 = idx >> 5, cc2 = idx & 31;
          float s = 0.0f;
#pragma unroll
          for (int t = 0; t < 32; ++t)
            s += Lb[base + r2][b0 + t] * Us[b0 + cc2][b0 + t];
          pv[e] = s;
        }
      }
      __syncthreads();
#pragma unroll
      for (int e = 0; e < 12; ++e) {
        int idx = tid + e * 256;
        if (idx < cnt) {
          int r2 = idx >> 5, cc2 = idx & 31;
          Lb[base + r2][b0 + cc2] = pv[e];
        }
      }
      __syncthreads();
      // ---- rank-32 trailing update (lower incl diag) ----
      int tot = nbl * nbl;
      for (int idx = tid; idx < tot; idx += 256) {
        int i = idx / nbl, j = idx - i * nbl;
        if (j <= i) {
          float4 a0 = *(const float4*)&Lb[base + i][b0];
          float4 a1 = *(const float4*)&Lb[base + i][b0 + 4];
          float4 a2 = *(const float4*)&Lb[base + i][b0 + 8];
          float4 a3 = *(const float4*)&Lb[base + i][b0 + 12];
          float4 a4 = *(const float4*)&Lb[base + i][b0 + 16];
          float4 a5 = *(const float4*)&Lb[base + i][b0 + 20];
          float4 a6 = *(const float4*)&Lb[base + i][b0 + 24];
          float4 a7 = *(const float4*)&Lb[base + i][b0 + 28];
          float4 b0v = *(const float4*)&Lb[base + j][b0];
          float4 b1v = *(const float4*)&Lb[base + j][b0 + 4];
          float4 b2v = *(const float4*)&Lb[base + j][b0 + 8];
          float4 b3v = *(const float4*)&Lb[base + j][b0 + 12];
          float4 b4v = *(const float4*)&Lb[base + j][b0 + 16];
          float4 b5v = *(const float4*)&Lb[base + j][b0 + 20];
          float4 b6v = *(const float4*)&Lb[base + j][b0 + 24];
          float4 b7v = *(const float4*)&Lb[base + j][b0 + 28];
          float s = a0.x*b0v.x + a0.y*b0v.y + a0.z*b0v.z + a0.w*b0v.w
                  + a1.x*b1v.x + a1.y*b1v.y + a1.z*b1v.z + a1.w*b1v.w
                  + a2.x*b2v.x + a2.y*b2v.y + a2.z*b2v.z + a2.w*b2v.w
                  + a3.x*b3v.x + a3.y*b3v.y + a3.z*b3v.z + a3.w*b3v.w
                  + a4.x*b4v.x + a4.y*b4v.y + a4.z*b4v.z + a4.w*b4v.w
                  + a5.x*b5v.x + a5.y*b5v.y + a5.z*b5v.z + a5.w*b5v.w
                  + a6.x*b6v.x + a6.y*b6v.y + a6.z*b6v.z + a6.w*b6v.w
                  + a7.x*b7v.x + a7.y*b7v.y + a7.z*b7v.z + a7.w*b7v.w;
          Lb[base + i][base + j] -= s;
        }
      }
      __syncthreads();
    }
  }
  // ---- assemble off-diag U blocks: U_ij = -V_i * (sum_t L_it U_tj) ----
  {
    int rr2 = tid >> 3, cc0 = (tid & 7) * 4;
#pragma unroll 1
    for (int d = 1; d <= 3; ++d) {
      int nb = 4 - d;
#pragma unroll 1
      for (int blk = 0; blk < nb; ++blk) {
        int bi = blk + d, bj = blk;
        float s0 = 0, s1 = 0, s2 = 0, s3 = 0;
        for (int t = 32 * bj; t < 32 * bi; ++t) {
          float a = Lb[32 * bi + rr2][t];
          const float4 u4 = *(const float4*)&Us[t][32 * bj + cc0];
          s0 += a * u4.x; s1 += a * u4.y; s2 += a * u4.z; s3 += a * u4.w;
        }
        float4 o = {s0, s1, s2, s3};
        *(float4*)&un.a.Tl[blk][rr2][cc0] = o;
      }
      __syncthreads();
#pragma unroll 1
      for (int blk = 0; blk < nb; ++blk) {
        int bi = blk + d, bj = blk;
        float s0 = 0, s1 = 0, s2 = 0, s3 = 0;
#pragma unroll
        for (int tq = 0; tq < 32; tq += 4) {
          float4 a4 = *(const float4*)&Us[32 * bi + rr2][32 * bi + tq];
#pragma unroll
          for (int e = 0; e < 4; ++e) {
            const float4 t4 = *(const float4*)&un.a.Tl[blk][tq + e][cc0];
            float ae = (&a4.x)[e];
            s0 += ae * t4.x; s1 += ae * t4.y; s2 += ae * t4.z; s3 += ae * t4.w;
          }
        }
        float4 o = {-s0, -s1, -s2, -s3};
        *(float4*)&Us[32 * bi + rr2][32 * bj + cc0] = o;
      }
      __syncthreads();
    }
  }
  // ---- write L, U, UT ----
  for (int idx = tid; idx < NB * 32; idx += 256) {
    int i = idx >> 5, f = idx & 31;
    *(float4*)(M + (size_t)(kr + i) * N + kr + 4 * f) = *(const float4*)&Lb[i][4 * f];
    *(float4*)(U + (size_t)i * NB + 4 * f) = *(const float4*)&Us[i][4 * f];
    float4 v;
    v.x = Us[4 * f + 0][i]; v.y = Us[4 * f + 1][i];
    v.z = Us[4 * f + 2][i]; v.w = Us[4 * f + 3][i];
    *(float4*)(UT + (size_t)i * NB + 4 * f) = v;
  }
}

// ---------------- panel TRSM as GEMM: P := P_old * U^T ----------------
__global__ __launch_bounds__(256) void k_trsm(float* __restrict__ M,
                                              const float* __restrict__ UT, int k0) {
  __shared__ float Ut[NB][LSTR];
  __shared__ float At[16][TSTR];
  int tid = threadIdx.x;
  int r0 = k0 + NB + blockIdx.x * NB;
  for (int idx = tid; idx < NB * 32; idx += 256) {
    int t = idx >> 5, f = idx & 31;
    *(float4*)&Ut[t][4 * f] = *(const float4*)(UT + (size_t)t * NB + 4 * f);
  }
  int i0 = (tid >> 4) * 8, j0 = (tid & 15) * 8;
  float acc[8][8] = {};
  for (int tch = 0; tch < NB; tch += 16) {
    for (int idx = tid; idx < 512; idx += 256) {
      int r = idx >> 2, q = idx & 3;
      const float4 v = *(const float4*)(M + (size_t)(r0 + r) * N + k0 + tch + 4 * q);
      At[4 * q + 0][r] = v.x; At[4 * q + 1][r] = v.y;
      At[4 * q + 2][r] = v.z; At[4 * q + 3][r] = v.w;
    }
    __syncthreads();
#pragma unroll 4
    for (int t = 0; t < 16; ++t) {
      float4 a0 = *(const float4*)&At[t][i0];
      float4 a1 = *(const float4*)&At[t][i0 + 4];
      float4 u0 = *(const float4*)&Ut[tch + t][j0];
      float4 u1 = *(const float4*)&Ut[tch + t][j0 + 4];
      float av[8] = {a0.x, a0.y, a0.z, a0.w, a1.x, a1.y, a1.z, a1.w};
      float uv[8] = {u0.x, u0.y, u0.z, u0.w, u1.x, u1.y, u1.z, u1.w};
#pragma unroll
      for (int q = 0; q < 8; ++q)
#pragma unroll
        for (int w = 0; w < 8; ++w) acc[q][w] += av[q] * uv[w];
    }
    __syncthreads();
  }
  for (int q = 0; q < 8; ++q) {
    float* mp = M + (size_t)(r0 + i0 + q) * N + k0 + j0;
    float4 x0 = {acc[q][0], acc[q][1], acc[q][2], acc[q][3]};
    float4 x1 = {acc[q][4], acc[q][5], acc[q][6], acc[q][7]};
    *(float4*)mp = x0; *((float4*)mp + 1) = x1;
  }
}

// ---------------- fused forward solve step k ----------------
__global__ __launch_bounds__(256) void k_fsolve(float* __restrict__ S,
                                                float* __restrict__ X,
                                                const float* __restrict__ M,
                                                const float* __restrict__ UTk,
                                                int k0) {
  __shared__ float Xl[NB][BSTR];
  __shared__ float Aa[16][TSTR];
  __shared__ float Bb[16][BSTR];
  int tid = threadIdx.x;
  int b0 = blockIdx.x * 64;
  int d = blockIdx.y;
  int i0g = k0 + d * NB;
  int ii = (tid >> 3) * 4, bl = (tid & 7) * 8;
  float acc[4][8] = {};
  for (int tch = 0; tch < NB; tch += 16) {
    for (int idx = tid; idx < 512; idx += 256) {
      int t = idx >> 5, f = idx & 31;
      *(float4*)&Aa[t][4 * f] = *(const float4*)(UTk + (size_t)(tch + t) * NB + 4 * f);
    }
    {
      int t = tid >> 4, f = tid & 15;
      *(float4*)&Bb[t][4 * f] = *(const float4*)(S + (size_t)(k0 + tch + t) * NRHS + b0 + 4 * f);
    }
    __syncthreads();
#pragma unroll 4
    for (int t = 0; t < 16; ++t) {
      float4 a0 = *(const float4*)&Aa[t][ii];
      float4 b0v = *(const float4*)&Bb[t][bl];
      float4 b1v = *(const float4*)&Bb[t][bl + 4];
      float av[4] = {a0.x, a0.y, a0.z, a0.w};
      float bv[8] = {b0v.x, b0v.y, b0v.z, b0v.w, b1v.x, b1v.y, b1v.z, b1v.w};
#pragma unroll
      for (int q = 0; q < 4; ++q)
#pragma unroll
        for (int w = 0; w < 8; ++w) acc[q][w] += av[q] * bv[w];
    }
    __syncthreads();
  }
  if (d == 0) {
    for (int q = 0; q < 4; ++q) {
      float* xp = X + (size_t)(k0 + ii + q) * NRHS + b0 + bl;
      float4 x0 = {acc[q][0], acc[q][1], acc[q][2], acc[q][3]};
      float4 x1 = {acc[q][4], acc[q][5], acc[q][6], acc[q][7]};
      *(float4*)xp = x0; *((float4*)xp + 1) = x1;
    }
    return;
  }
  for (int q = 0; q < 4; ++q) {
    float4 x0 = {acc[q][0], acc[q][1], acc[q][2], acc[q][3]};
    float4 x1 = {acc[q][4], acc[q][5], acc[q][6], acc[q][7]};
    *(float4*)&Xl[ii + q][bl] = x0; *(float4*)&Xl[ii + q][bl + 4] = x1;
  }
  __syncthreads();
  float acc2[4][8] = {};
  for (int tch = 0; tch < NB; tch += 16) {
    for (int idx = tid; idx < 512; idx += 256) {
      int r = idx >> 2, q = idx & 3;
      const float4 v = *(const float4*)(M + (size_t)(i0g + r) * N + k0 + tch + 4 * q);
      Aa[4 * q + 0][r] = v.x; Aa[4 * q + 1][r] = v.y;
      Aa[4 * q + 2][r] = v.z; Aa[4 * q + 3][r] = v.w;
    }
    __syncthreads();
#pragma unroll 4
    for (int t = 0; t < 16; ++t) {
      float4 a0 = *(const float4*)&Aa[t][ii];
      float4 b0v = *(const float4*)&Xl[tch + t][bl];
      float4 b1v = *(const float4*)&Xl[tch + t][bl + 4];
      float av[4] = {a0.x, a0.y, a0.z, a0.w};
      float bv[8] = {b0v.x, b0v.y, b0v.z, b0v.w, b1v.x, b1v.y, b1v.z, b1v.w};
#pragma unroll
      for (int q = 0; q < 4; ++q)
#pragma unroll
        for (int w = 0; w < 8; ++w) acc2[q][w] += av[q] * bv[w];
    }
    __syncthreads();
  }
  for (int q = 0; q < 4; ++q) {
    float* sp = S + (size_t)(i0g + ii + q) * NRHS + b0 + bl;
    float4 x0 = *(float4*)sp, x1 = *((float4*)sp + 1);
    x0.x -= acc2[q][0]; x0.y -= acc2[q][1]; x0.z -= acc2[q][2]; x0.w -= acc2[q][3];
    x1.x -= acc2[q][4]; x1.y -= acc2[q][5]; x1.z -= acc2[q][6]; x1.w -= acc2[q][7];
    *(float4*)sp = x0; *((float4*)sp + 1) = x1;
  }
}

// ---------------- fused backward solve step k (descending) ----------------
__global__ __launch_bounds__(256) void k_bsolve(float* __restrict__ X,
                                                float* __restrict__ S,
                                                const float* __restrict__ M,
                                                const float* __restrict__ Uk,
                                                int k0) {
  __shared__ float Xl[NB][BSTR];
  __shared__ float Aa[16][TSTR];
  __shared__ float Bb[16][BSTR];
  int tid = threadIdx.x;
  int b0 = blockIdx.x * 64;
  int d = blockIdx.y;
  int i0g = k0 - d * NB;
  int ii = (tid >> 3) * 4, bl = (tid & 7) * 8;
  float acc[4][8] = {};
  for (int tch = 0; tch < NB; tch += 16) {
    for (int idx = tid; idx < 512; idx += 256) {
      int t = idx >> 5, f = idx & 31;
      *(float4*)&Aa[t][4 * f] = *(const float4*)(Uk + (size_t)(tch + t) * NB + 4 * f);
    }
    {
      int t = tid >> 4, f = tid & 15;
      *(float4*)&Bb[t][4 * f] = *(const float4*)(X + (size_t)(k0 + tch + t) * NRHS + b0 + 4 * f);
    }
    __syncthreads();
#pragma unroll 4
    for (int t = 0; t < 16; ++t) {
      float4 a0 = *(const float4*)&Aa[t][ii];
      float4 b0v = *(const float4*)&Bb[t][bl];
      float4 b1v = *(const float4*)&Bb[t][bl + 4];
      float av[4] = {a0.x, a0.y, a0.z, a0.w};
      float bv[8] = {b0v.x, b0v.y, b0v.z, b0v.w, b1v.x, b1v.y, b1v.z, b1v.w};
#pragma unroll
      for (int q = 0; q < 4; ++q)
#pragma unroll
        for (int w = 0; w < 8; ++w) acc[q][w] += av[q] * bv[w];
    }
    __syncthreads();
  }
  if (d == 0) {
    for (int q = 0; q < 4; ++q) {
      float* sp = S + (size_t)(k0 + ii + q) * NRHS + b0 + bl;
      float4 x0 = {acc[q][0], acc[q][1], acc[q][2], acc[q][3]};
      float4 x1 = {acc[q][4], acc[q][5], acc[q][6], acc[q][7]};
      *(float4*)sp = x0; *((float4*)sp + 1) = x1;
    }
    return;
  }
  for (int q = 0; q < 4; ++q) {
    float4 x0 = {acc[q][0], acc[q][1], acc[q][2], acc[q][3]};
    float4 x1 = {acc[q][4], acc[q][5], acc[q][6], acc[q][7]};
    *(float4*)&Xl[ii + q][bl] = x0; *(float4*)&Xl[ii + q][bl + 4] = x1;
  }
  __syncthreads();
  float acc2[4][8] = {};
  for (int tch = 0; tch < NB; tch += 16) {
    for (int idx = tid; idx < 512; idx += 256) {
      int t = idx >> 5, f = idx & 31;
      *(float4*)&Aa[t][4 * f] = *(const float4*)(M + (size_t)(k0 + tch + t) * N + i0g + 4 * f);
    }
    __syncthreads();
#pragma unroll 4
    for (int t = 0; t < 16; ++t) {
      float4 a0 = *(const float4*)&Aa[t][ii];
      float4 b0v = *(const float4*)&Xl[tch + t][bl];
      float4 b1v = *(const float4*)&Xl[tch + t][bl + 4];
      float av[4] = {a0.x, a0.y, a0.z, a0.w};
      float bv[8] = {b0v.x, b0v.y, b0v.z, b0v.w, b1v.x, b1v.y, b1v.z, b1v.w};
#pragma unroll
      for (int q = 0; q < 4; ++q)
#pragma unroll
        for (int w = 0; w < 8; ++w) acc2[q][w] += av[q] * bv[w];
    }
    __syncthreads();
  }
  for (int q = 0; q < 4; ++q) {
    float* xp = X + (size_t)(i0g + ii + q) * NRHS + b0 + bl;
    float4 x0 = *(float4*)xp, x1 = *((float4*)xp + 1);
    x0.x -= acc2[q][0]; x0.y -= acc2[q][1]; x0.z -= acc2[q][2]; x0.w -= acc2[q][3];
    x1.x -= acc2[q][4]; x1.y -= acc2[q][5]; x1.z -= acc2[q][6]; x1.w -= acc2[q][7];
    *(float4*)xp = x0; *((float4*)xp + 1) = x1;
  }
}

// ---------------- denom + normalize + transpose to output ----------------
__global__ __launch_bounds__(256) void k_final(const float* __restrict__ S,
                                               const float* __restrict__ K,
                                               const float* __restrict__ a_ptr,
                                               float* __restrict__ out) {
  __shared__ float red[256];
  int b = blockIdx.x, tid = threadIdx.x;
  float s = 0.0f;
  for (int i = tid; i < N; i += 256) s += S[(size_t)i * NRHS + b] * K[(size_t)b * N + i];
  red[tid] = s; __syncthreads();
  for (int w = 128; w > 0; w >>= 1) { if (tid < w) red[tid] += red[tid + w]; __syncthreads(); }
  float inv = 1.0f / (a_ptr[0] * red[0]);
  for (int i = tid; i < N; i += 256) out[(size_t)b * N + i] = S[(size_t)i * NRHS + b] * inv;
}

extern "C" void kernel_launch(void* const* d_in, const int* in_sizes, int n_in,
                              void* d_out, int out_size, void* d_ws, size_t ws_size,
                              hipStream_t stream) {
  const float* Kb    = (const float*)d_in[0];
  const float* a     = (const float*)d_in[1];
  const float* exc   = (const float*)d_in[2];
  const float* imp   = (const float*)d_in[3];
  const float* Phi   = (const float*)d_in[4];
  const float* gamma = (const float*)d_in[5];
  float* out = (float*)d_out;

  float* M  = (float*)d_ws;                        // n*n            (64 MiB)
  float* S  = M + (size_t)N * N;                   // n*NRHS         (8 MiB)
  float* X  = S + (size_t)N * NRHS;                // n*NRHS         (8 MiB)
  float* U  = X + (size_t)N * NRHS;                // 32 * 128*128   (2 MiB)
  float* UT = U + (size_t)32 * NB * NB;            // 32 * 128*128   (2 MiB)
  float* c  = UT + (size_t)32 * NB * NB;           // scalars

  k_scalars<<<1, 256, 0, stream>>>(imp, exc, gamma, c);
  k_build_M<<<N * N / 1024, 256, 0, stream>>>(Phi, c, M);
  k_transpose<<<dim3(N / 32, NRHS / 32), 256, 0, stream>>>(Kb, S);

  // potrf(0) standalone (no panel update, no trailing tiles)
  k_syrk_potrf<<<1, 256, 0, stream>>>(M, U, UT, 0, -1);
  for (int k = 0; k <= 30; ++k) {
    int k0 = k * NB;
    k_trsm<<<31 - k, 256, 0, stream>>>(M, UT + (size_t)k * NB * NB, k0);
    int T = 31 - k;
    int pairs = (T * (T + 1)) / 2;   // block 0 = lookahead potrf(k+1), rest = tri syrk tiles
    k_syrk_potrf<<<pairs, 256, 0, stream>>>(M, U + (size_t)(k + 1) * NB * NB,
                                            UT + (size_t)(k + 1) * NB * NB, k + 1, k0);
  }
  for (int k = 0; k < 32; ++k)
    k_fsolve<<<dim3(NRHS / 64, 32 - k), 256, 0, stream>>>(S, X, M, UT + (size_t)k * NB * NB, k * NB);
  for (int k = 31; k >= 0; --k)
    k_bsolve<<<dim3(NRHS / 64, k + 1), 256, 0, stream>>>(X, S, M, U + (size_t)k * NB * NB, k * NB);
  k_final<<<NRHS, 256, 0, stream>>>(S, Kb, a, out);
}